// Round 11
// baseline (503.272 us; speedup 1.0000x reference)
//
#include <hip/hip_runtime.h>
#include <hip/hip_bf16.h>
#include <stdint.h>

#define SEQ 2048
#define DDIM 768
#define KF 24
#define NKV 48

typedef unsigned short ushort_t;
typedef __attribute__((ext_vector_type(8))) short short8;
typedef __attribute__((ext_vector_type(4))) float f32x4;

typedef __attribute__((address_space(3))) uint32_t lds_u32;
typedef __attribute__((address_space(1))) uint32_t glb_u32;

__device__ __forceinline__ unsigned short f2bf(float f) {
    union { float f; uint32_t u; } v; v.f = f;
    uint32_t u = v.u;
    return (unsigned short)((u + 0x7fff + ((u >> 16) & 1)) >> 16);
}

// Image layout for a [128 rows][64 k] bf16 slab (16 KB), XOR-swizzled:
//   idx(row,k) = row*64 + (((k>>3) ^ (row&7))<<3) + (k&7)

// ---------------- prep: pack x ----------------
__global__ void k_pack_x(const float* __restrict__ x, ushort_t* __restrict__ xpk) {
    int b = blockIdx.x;            // tt*12 + ks
    int tt = b / 12, ks = b % 12;
    int tid = threadIdx.x;
    ushort_t* dst = xpk + (size_t)b * 8192;
    const float* src = x + (size_t)tt * 128 * DDIM + ks * 64;
#pragma unroll
    for (int p = 0; p < 4; ++p) {
        int s = p * 256 + tid;
        int row = s >> 3, sl = s & 7;
        const float* rp = src + (size_t)row * DDIM + sl * 8;
        float4 a = *(const float4*)rp;
        float4 c = *(const float4*)(rp + 4);
        ushort_t v[8] = {f2bf(a.x), f2bf(a.y), f2bf(a.z), f2bf(a.w),
                         f2bf(c.x), f2bf(c.y), f2bf(c.z), f2bf(c.w)};
        *(uint4*)(dst + row * 64 + ((sl ^ (row & 7)) << 3)) = *(uint4*)v;
    }
}

// ---------------- prep: pack M transposed ----------------
__global__ void k_pack_M(const float* __restrict__ Mp, const float* __restrict__ Mm,
                         ushort_t* __restrict__ Mpk) {
    __shared__ ushort_t lt[128 * 66];
    int b = blockIdx.x;            // (kv*6 + et)*12 + ks
    int kv = b / 72; int rem = b % 72; int et = rem / 12, ks = rem % 12;
    const float* src = ((kv < KF) ? Mp + (size_t)kv * DDIM * DDIM
                                  : Mm + (size_t)(kv - KF) * DDIM * DDIM)
                       + (size_t)(ks * 64) * DDIM + et * 128;
    int tid = threadIdx.x;
#pragma unroll
    for (int p = 0; p < 32; ++p) {
        int lin = p * 256 + tid;
        int d = lin >> 7, e = lin & 127;
        lt[e * 66 + d] = f2bf(src[(size_t)d * DDIM + e]);
    }
    __syncthreads();
    ushort_t* dst = Mpk + (size_t)b * 8192;
#pragma unroll
    for (int p = 0; p < 4; ++p) {
        int s = p * 256 + tid; int row = s >> 3, sl = s & 7;
        ushort_t v[8];
#pragma unroll
        for (int j = 0; j < 8; ++j) v[j] = lt[row * 66 + sl * 8 + j];
        *(uint4*)(dst + row * 64 + ((sl ^ (row & 7)) << 3)) = *(uint4*)v;
    }
}

// ---------------- prep: build Toeplitz blocks (17 lag slots, slot 0 = zeros) ----------------
__global__ void k_build_T(const float* __restrict__ phi, ushort_t* __restrict__ Tpk) {
    __shared__ float phiL[256];
    int b = blockIdx.x;            // kv*17 + slot
    int kv = b / 17, slot = b % 17;
    int dm = slot - 1;             // lag block; dm = -1 -> all zeros
    int k = kv % KF; bool neg = kv >= KF;
    int tid = threadIdx.x;
    int tau = 128 * dm - 127 + tid;
    float v = 0.f;
    if (tid < 255 && tau >= 0 && tau < SEQ) {
        v = phi[(size_t)tau * KF + k];
        if (neg && (tau & 1)) v = -v;
    }
    phiL[tid] = v;
    __syncthreads();
    ushort_t* dst = Tpk + (size_t)b * 2 * 8192;
#pragma unroll
    for (int h = 0; h < 2; ++h) {
#pragma unroll
        for (int p = 0; p < 4; ++p) {
            int s = p * 256 + tid; int row = s >> 3, sl = s & 7;
            ushort_t v8[8];
#pragma unroll
            for (int j = 0; j < 8; ++j) {
                int col = h * 64 + sl * 8 + j;
                v8[j] = f2bf(phiL[row - col + 127]);
            }
            *(uint4*)(dst + h * 8192 + row * 64 + ((sl ^ (row & 7)) << 3)) = *(uint4*)v8;
        }
    }
}

// ---------------- shared fragment-read helpers ----------------

__device__ __forceinline__ void read_frags(const ushort_t* As, const ushort_t* Bs,
                                           int lane, int wm, int wn, int kk,
                                           short8 av[4], short8 bv[4]) {
    int slot = kk * 4 + (lane >> 4);
#pragma unroll
    for (int m = 0; m < 4; ++m) {
        int row = wm * 64 + m * 16 + (lane & 15);
        av[m] = *(const short8*)(As + row * 64 + ((slot ^ (row & 7)) << 3));
    }
#pragma unroll
    for (int n = 0; n < 4; ++n) {
        int row = wn * 64 + n * 16 + (lane & 15);
        bv[n] = *(const short8*)(Bs + row * 64 + ((slot ^ (row & 7)) << 3));
    }
}

__device__ __forceinline__ void mfma16(const short8 av[4], const short8 bv[4], f32x4 acc[4][4]) {
    __builtin_amdgcn_s_setprio(1);
#pragma unroll
    for (int m = 0; m < 4; ++m)
#pragma unroll
        for (int n = 0; n < 4; ++n)
            acc[m][n] = __builtin_amdgcn_mfma_f32_16x16x32_bf16(av[m], bv[n], acc[m][n], 0, 0, 0);
    __builtin_amdgcn_s_setprio(0);
}

// ---------------- stage A (r5 pipelined): Apk[kv][et][tt][h][img] ----------------
__global__ __launch_bounds__(256, 2)
void k_gemm_A(const ushort_t* __restrict__ Mpk, const ushort_t* __restrict__ xpk,
              ushort_t* __restrict__ Apk) {
    __shared__ ushort_t smem[2][2][8192];
    int bid = blockIdx.x;
    int kv = bid / 96; int rem = bid % 96; int et = rem / 16, tt = rem % 16;
    const ushort_t* Abase = Mpk + ((size_t)(kv * 6 + et) * 12) * 8192;
    const ushort_t* Bbase = xpk + (size_t)(tt * 12) * 8192;
    int tid = threadIdx.x, lane = tid & 63, wave = tid >> 6;
    int wm = wave >> 1, wn = wave & 1;

    auto stage4 = [&](const ushort_t* src, ushort_t* dst) {
        const char* s = (const char*)src + wave * 4096 + lane * 16;
        char* l = (char*)dst + wave * 4096;
#pragma unroll
        for (int p = 0; p < 4; ++p)
            __builtin_amdgcn_global_load_lds((const glb_u32*)(s + p * 1024),
                                             (lds_u32*)(l + p * 1024), 16, 0, 0);
    };

    f32x4 acc[4][4];
#pragma unroll
    for (int m = 0; m < 4; ++m)
#pragma unroll
        for (int n = 0; n < 4; ++n) acc[m][n] = (f32x4){0.f, 0.f, 0.f, 0.f};

    stage4(Abase, smem[0][0]);
    stage4(Bbase, smem[0][1]);

    for (int s = 0; s < 12; ++s) {
        int c = s & 1;
        bool more = (s + 1 < 12);
        if (more) {
            stage4(Abase + (s + 1) * 8192, smem[c ^ 1][0]);
            asm volatile("s_waitcnt vmcnt(4)" ::: "memory");
        } else {
            asm volatile("s_waitcnt vmcnt(0)" ::: "memory");
        }
        __builtin_amdgcn_s_barrier();
        __builtin_amdgcn_sched_barrier(0);

        const ushort_t* As = smem[c][0];
        const ushort_t* Bs = smem[c][1];
        short8 av0[4], bv0[4], av1[4], bv1[4];
        read_frags(As, Bs, lane, wm, wn, 0, av0, bv0);
        asm volatile("s_waitcnt lgkmcnt(0)" ::: "memory");
        __builtin_amdgcn_sched_barrier(0);
        read_frags(As, Bs, lane, wm, wn, 1, av1, bv1);
        if (more) stage4(Bbase + (s + 1) * 8192, smem[c ^ 1][1]);
        mfma16(av0, bv0, acc);
        asm volatile("s_waitcnt lgkmcnt(0)" ::: "memory");
        __builtin_amdgcn_sched_barrier(0);
        mfma16(av1, bv1, acc);
        __builtin_amdgcn_s_barrier();
    }

    ushort_t* sm = &smem[0][0][0];
#pragma unroll
    for (int m = 0; m < 4; ++m) {
        int rb = wm * 64 + m * 16 + ((lane >> 4) << 2);
#pragma unroll
        for (int n = 0; n < 4; ++n) {
            int cb = wn * 64 + n * 16 + (lane & 15);
            int h = cb >> 6, c6 = cb & 63, sl = c6 >> 3, j = c6 & 7;
#pragma unroll
            for (int r = 0; r < 4; ++r) {
                int row = rb + r;
                sm[h * 8192 + row * 64 + ((sl ^ (row & 7)) << 3) + j] = f2bf(acc[m][n][r]);
            }
        }
    }
    __syncthreads();
    uint4* d4 = (uint4*)(Apk + ((size_t)((kv * 6 + et) * 16 + tt) * 2) * 8192);
    const uint4* s4 = (const uint4*)sm;
#pragma unroll
    for (int p = 0; p < 8; ++p) d4[p * 256 + tid] = s4[p * 256 + tid];
}

// ---------------- stage B: stream-K, 512 uniform blocks x 153 steps ----------------
// Step space: et(6) x tiles i1(0..15, 96*(i1+1) steps: jj outer, kv inner, h inner).
// Total 78336 = 512*153. Block owns steps [lid*153, +153); flushes a private
// 128x128 f32 slab per tile segment; slab id = lid + tile (injective).
__global__ __launch_bounds__(256, 2)
void k_gemm_Bsk(const ushort_t* __restrict__ Tpk, const ushort_t* __restrict__ Apk,
                float* __restrict__ slab) {
    __shared__ ushort_t smem[2][2][8192];   // [buf][0=T, 1=A]

    int bid = blockIdx.x;
    int lid = (bid & 7) * 64 + (bid >> 3);   // bijective XCD swizzle, 512 = 8*64
    int g0 = lid * 153;

    // decompose g0 -> (et, i1, jj, kv, h)
    int ce = g0 / 13056;                     // 13056 steps per et-panel
    int r  = g0 - ce * 13056;
    int ci = 0;
    while (48 * (ci + 1) * (ci + 2) <= r) ++ci;   // tile prefix = 48*i1*(i1+1)
    int rr = r - 48 * ci * (ci + 1);
    int cj = rr / 96;
    int q  = rr - cj * 96;
    int ck = q >> 1, ch = q & 1;

    // next-step cursor
    int ne = ce, ni = ci, nj = cj, nk = ck, nh = ch;
    auto adv = [&]() {
        nh ^= 1;
        if (!nh) {
            if (++nk == NKV) { nk = 0;
                if (++nj > ni) { nj = 0;
                    if (++ni == 16) { ni = 0; ++ne; } } }
        }
    };
    adv();

    int tid = threadIdx.x, lane = tid & 63, wave = tid >> 6;
    int wm = wave >> 1, wn = wave & 1;

    f32x4 acc[4][4];
#pragma unroll
    for (int m = 0; m < 4; ++m)
#pragma unroll
        for (int n = 0; n < 4; ++n) acc[m][n] = (f32x4){0.f, 0.f, 0.f, 0.f};

    auto timgf = [&](int i1_, int jj_, int kv_, int h_) -> const ushort_t* {
        return Tpk + ((size_t)((kv_ * 17 + (i1_ - jj_ + 1)) * 2 + h_)) * 8192;
    };
    auto aimgf = [&](int et_, int jj_, int kv_, int h_) -> const ushort_t* {
        return Apk + ((size_t)(((kv_ * 6 + et_) * 16 + jj_) * 2 + h_)) * 8192;
    };
    auto stage4 = [&](const ushort_t* src, ushort_t* dst) {
        const char* s = (const char*)src + wave * 4096 + lane * 16;
        char* l = (char*)dst + wave * 4096;
#pragma unroll
        for (int p = 0; p < 4; ++p)
            __builtin_amdgcn_global_load_lds((const glb_u32*)(s + p * 1024),
                                             (lds_u32*)(l + p * 1024), 16, 0, 0);
    };

    stage4(timgf(ci, cj, ck, ch), smem[0][0]);
    stage4(aimgf(ce, cj, ck, ch), smem[0][1]);

    for (int s = 0; s < 153; ++s) {
        int c = s & 1;
        bool more = (s + 1 < 153);

        if (more) {
            stage4(timgf(ni, nj, nk, nh), smem[c ^ 1][0]);
            asm volatile("s_waitcnt vmcnt(4)" ::: "memory");   // this step's 8 landed
        } else {
            asm volatile("s_waitcnt vmcnt(0)" ::: "memory");
        }
        __builtin_amdgcn_s_barrier();
        __builtin_amdgcn_sched_barrier(0);

        const ushort_t* As = smem[c][0];
        const ushort_t* Bs = smem[c][1];
        short8 av[2][4], bv[2][4];
#pragma unroll
        for (int kk = 0; kk < 2; ++kk) {
            int slot = kk * 4 + (lane >> 4);
#pragma unroll
            for (int m = 0; m < 4; ++m) {
                int row = wm * 64 + m * 16 + (lane & 15);
                av[kk][m] = *(const short8*)(As + row * 64 + ((slot ^ (row & 7)) << 3));
            }
#pragma unroll
            for (int n = 0; n < 4; ++n) {
                int row = wn * 64 + n * 16 + (lane & 15);
                bv[kk][n] = *(const short8*)(Bs + row * 64 + ((slot ^ (row & 7)) << 3));
            }
        }
        if (more) stage4(aimgf(ne, nj, nk, nh), smem[c ^ 1][1]);

        asm volatile("s_waitcnt lgkmcnt(0)" ::: "memory");
        __builtin_amdgcn_sched_barrier(0);

        __builtin_amdgcn_s_setprio(1);
#pragma unroll
        for (int kk = 0; kk < 2; ++kk)
#pragma unroll
            for (int m = 0; m < 4; ++m)
#pragma unroll
                for (int n = 0; n < 4; ++n)
                    acc[m][n] = __builtin_amdgcn_mfma_f32_16x16x32_bf16(av[kk][m], bv[kk][n], acc[m][n], 0, 0, 0);
        __builtin_amdgcn_s_setprio(0);
        __builtin_amdgcn_s_barrier();

        // flush at tile boundary / end of range
        if (!more || ni != ci || ne != ce) {
            float* dst = slab + (size_t)(lid + ce * 16 + ci) * 16384;
#pragma unroll
            for (int m = 0; m < 4; ++m) {
                int rb = wm * 64 + m * 16 + ((lane >> 4) << 2);
#pragma unroll
                for (int n = 0; n < 4; ++n) {
                    int cb = wn * 64 + n * 16 + (lane & 15);
#pragma unroll
                    for (int rr2 = 0; rr2 < 4; ++rr2) {
                        dst[(rb + rr2) * 128 + cb] = acc[m][n][rr2];
                        acc[m][n][rr2] = 0.f;
                    }
                }
            }
        }
        ce = ne; ci = ni; cj = nj; ck = nk; ch = nh;
        adv();
    }
}

// out[s,e] = sum of slab partials for tile (i1 = s>>7, et = e>>7)
__global__ void k_reduce(const float* __restrict__ slab, float* __restrict__ out, int n4) {
    int idx = blockIdx.x * blockDim.x + threadIdx.x;
    if (idx < n4) {
        int srow = idx / (DDIM / 4);
        int e4 = idx % (DDIM / 4);
        int i1 = srow >> 7;
        int et = e4 >> 5;                    // e4 in float4 units; et = (e4*4)>>7
        int t = et * 16 + i1;
        int T0 = et * 13056 + 48 * i1 * (i1 + 1);
        int len = 96 * (i1 + 1);
        int bs = T0 / 153;
        int be = (T0 + len - 1) / 153;
        size_t elem = (size_t)(srow & 127) * 128 + ((e4 * 4) & 127);
        float4 s = {0.f, 0.f, 0.f, 0.f};
        for (int b = bs; b <= be; ++b) {
            float4 v = *(const float4*)(slab + (size_t)(b + t) * 16384 + elem);
            s.x += v.x; s.y += v.y; s.z += v.z; s.w += v.w;
        }
        ((float4*)out)[idx] = s;
    }
}

extern "C" void kernel_launch(void* const* d_in, const int* in_sizes, int n_in,
                              void* d_out, int out_size, void* d_ws, size_t ws_size,
                              hipStream_t stream) {
    (void)in_sizes; (void)n_in;
    const float* x   = (const float*)d_in[0];
    const float* phi = (const float*)d_in[1];
    const float* Mp  = (const float*)d_in[2];
    const float* Mm  = (const float*)d_in[3];
    float* out = (float*)d_out;

    char* ws = (char*)d_ws;
    size_t off = 0;
    auto alloc = [&](size_t bytes) { size_t o = off; off += (bytes + 255) & ~(size_t)255; return o; };
    size_t o_xpk = alloc((size_t)16 * 12 * 8192 * 2);                // 3.0 MB
    size_t o_Mpk = alloc((size_t)NKV * 6 * 12 * 8192 * 2);           // 56.6 MB (aliased by slab)
    size_t o_Tpk = alloc((size_t)NKV * 17 * 2 * 8192 * 2);           // 26.8 MB
    size_t o_Apk = alloc((size_t)NKV * 6 * 16 * 2 * 8192 * 2);       // 151.0 MB
    if (off > ws_size) {   // should never happen (~237 MB total; r9/r10 proved fits)
        hipMemsetAsync(d_out, 0, (size_t)out_size * 4, stream);
        return;
    }

    ushort_t* xpk = (ushort_t*)(ws + o_xpk);
    ushort_t* Mpk = (ushort_t*)(ws + o_Mpk);
    ushort_t* Tpk = (ushort_t*)(ws + o_Tpk);
    ushort_t* Apk = (ushort_t*)(ws + o_Apk);
    float*   slab = (float*)(ws + o_Mpk);   // alias: Mpk dead after gemm_A; 607*64KB = 39.8 <= 56.6 MB

    k_pack_x<<<16 * 12, 256, 0, stream>>>(x, xpk);
    k_pack_M<<<NKV * 6 * 12, 256, 0, stream>>>(Mp, Mm, Mpk);
    k_build_T<<<NKV * 17, 256, 0, stream>>>(phi, Tpk);
    k_gemm_A<<<NKV * 96, 256, 0, stream>>>(Mpk, xpk, Apk);
    k_gemm_Bsk<<<512, 256, 0, stream>>>(Tpk, Apk, slab);
    int n4 = SEQ * DDIM / 4;
    k_reduce<<<(n4 + 255) / 256, 256, 0, stream>>>(slab, out, n4);
}

// Round 12
// 379.172 us; speedup vs baseline: 1.3273x; 1.3273x over previous
//
#include <hip/hip_runtime.h>
#include <hip/hip_bf16.h>
#include <stdint.h>

#define SEQ 2048
#define DDIM 768
#define KF 24
#define NKV 48
#define NZC 8   // outz split-K slices (jj-chunk of 2)

typedef unsigned short ushort_t;
typedef __attribute__((ext_vector_type(8))) short short8;
typedef __attribute__((ext_vector_type(16))) float f32x16;

typedef __attribute__((address_space(3))) uint32_t lds_u32;
typedef __attribute__((address_space(1))) uint32_t glb_u32;

__device__ __forceinline__ unsigned short f2bf(float f) {
    union { float f; uint32_t u; } v; v.f = f;
    uint32_t u = v.u;
    return (unsigned short)((u + 0x7fff + ((u >> 16) & 1)) >> 16);
}

// Image layout for a [128 rows][64 k] bf16 slab (16 KB), XOR-swizzled:
//   idx(row,k) = row*64 + (((k>>3) ^ (row&7))<<3) + (k&7)

// ---------------- prep: pack x ----------------
__global__ void k_pack_x(const float* __restrict__ x, ushort_t* __restrict__ xpk) {
    int b = blockIdx.x;            // tt*12 + ks
    int tt = b / 12, ks = b % 12;
    int tid = threadIdx.x;
    ushort_t* dst = xpk + (size_t)b * 8192;
    const float* src = x + (size_t)tt * 128 * DDIM + ks * 64;
#pragma unroll
    for (int p = 0; p < 4; ++p) {
        int s = p * 256 + tid;
        int row = s >> 3, sl = s & 7;
        const float* rp = src + (size_t)row * DDIM + sl * 8;
        float4 a = *(const float4*)rp;
        float4 c = *(const float4*)(rp + 4);
        ushort_t v[8] = {f2bf(a.x), f2bf(a.y), f2bf(a.z), f2bf(a.w),
                         f2bf(c.x), f2bf(c.y), f2bf(c.z), f2bf(c.w)};
        *(uint4*)(dst + row * 64 + ((sl ^ (row & 7)) << 3)) = *(uint4*)v;
    }
}

// ---------------- prep: pack M transposed ----------------
__global__ void k_pack_M(const float* __restrict__ Mp, const float* __restrict__ Mm,
                         ushort_t* __restrict__ Mpk) {
    __shared__ ushort_t lt[128 * 66];
    int b = blockIdx.x;            // (kv*6 + et)*12 + ks
    int kv = b / 72; int rem = b % 72; int et = rem / 12, ks = rem % 12;
    const float* src = ((kv < KF) ? Mp + (size_t)kv * DDIM * DDIM
                                  : Mm + (size_t)(kv - KF) * DDIM * DDIM)
                       + (size_t)(ks * 64) * DDIM + et * 128;
    int tid = threadIdx.x;
#pragma unroll
    for (int p = 0; p < 32; ++p) {
        int lin = p * 256 + tid;
        int d = lin >> 7, e = lin & 127;
        lt[e * 66 + d] = f2bf(src[(size_t)d * DDIM + e]);
    }
    __syncthreads();
    ushort_t* dst = Mpk + (size_t)b * 8192;
#pragma unroll
    for (int p = 0; p < 4; ++p) {
        int s = p * 256 + tid; int row = s >> 3, sl = s & 7;
        ushort_t v[8];
#pragma unroll
        for (int j = 0; j < 8; ++j) v[j] = lt[row * 66 + sl * 8 + j];
        *(uint4*)(dst + row * 64 + ((sl ^ (row & 7)) << 3)) = *(uint4*)v;
    }
}

// ---------------- prep: build Toeplitz blocks (17 lag slots, slot 0 = zeros) ----------------
__global__ void k_build_T(const float* __restrict__ phi, ushort_t* __restrict__ Tpk) {
    __shared__ float phiL[256];
    int b = blockIdx.x;            // kv*17 + slot
    int kv = b / 17, slot = b % 17;
    int dm = slot - 1;             // lag block; dm = -1 -> all zeros
    int k = kv % KF; bool neg = kv >= KF;
    int tid = threadIdx.x;
    int tau = 128 * dm - 127 + tid;
    float v = 0.f;
    if (tid < 255 && tau >= 0 && tau < SEQ) {
        v = phi[(size_t)tau * KF + k];
        if (neg && (tau & 1)) v = -v;
    }
    phiL[tid] = v;
    __syncthreads();
    ushort_t* dst = Tpk + (size_t)b * 2 * 8192;
#pragma unroll
    for (int h = 0; h < 2; ++h) {
#pragma unroll
        for (int p = 0; p < 4; ++p) {
            int s = p * 256 + tid; int row = s >> 3, sl = s & 7;
            ushort_t v8[8];
#pragma unroll
            for (int j = 0; j < 8; ++j) {
                int col = h * 64 + sl * 8 + j;
                v8[j] = f2bf(phiL[row - col + 127]);
            }
            *(uint4*)(dst + h * 8192 + row * 64 + ((sl ^ (row & 7)) << 3)) = *(uint4*)v8;
        }
    }
}

// ---------------- 32x32x16 fragment helpers ----------------
// A/B operand: row = lane&31, k = (lane>>5)*8 within K=16 slice kq -> slot = kq*2 + (lane>>5)
// C/D: col = lane&31, row = (reg&3) + 8*(reg>>2) + 4*(lane>>5)   [verified m74/m101]

__device__ __forceinline__ void read_frags32(const ushort_t* As, const ushort_t* Bs,
                                             int lane, int wm, int wn, int kqb,
                                             short8 av[2][2], short8 bv[2][2]) {
    int l31 = lane & 31, hi = lane >> 5;
#pragma unroll
    for (int kq = 0; kq < 2; ++kq) {
        int slot = (kqb + kq) * 2 + hi;
#pragma unroll
        for (int mf = 0; mf < 2; ++mf) {
            int row = wm * 64 + mf * 32 + l31;
            av[kq][mf] = *(const short8*)(As + row * 64 + ((slot ^ (row & 7)) << 3));
        }
#pragma unroll
        for (int nf = 0; nf < 2; ++nf) {
            int row = wn * 64 + nf * 32 + l31;
            bv[kq][nf] = *(const short8*)(Bs + row * 64 + ((slot ^ (row & 7)) << 3));
        }
    }
}

__device__ __forceinline__ void mfma32p(const short8 av[2][2], const short8 bv[2][2],
                                        f32x16 acc[2][2]) {
    __builtin_amdgcn_s_setprio(1);
#pragma unroll
    for (int kq = 0; kq < 2; ++kq)
#pragma unroll
        for (int mf = 0; mf < 2; ++mf)
#pragma unroll
            for (int nf = 0; nf < 2; ++nf)
                acc[mf][nf] = __builtin_amdgcn_mfma_f32_32x32x16_bf16(
                    av[kq][mf], bv[kq][nf], acc[mf][nf], 0, 0, 0);
    __builtin_amdgcn_s_setprio(0);
}

// ---------------- stage A (r5 cadence, 32x32 MFMA): Apk[kv][et][tt][h][img] ----------------
__global__ __launch_bounds__(256, 2)
void k_gemm_A(const ushort_t* __restrict__ Mpk, const ushort_t* __restrict__ xpk,
              ushort_t* __restrict__ Apk) {
    __shared__ ushort_t smem[2][2][8192];
    int bid = blockIdx.x;
    int kv = bid / 96; int rem = bid % 96; int et = rem / 16, tt = rem % 16;
    const ushort_t* Abase = Mpk + ((size_t)(kv * 6 + et) * 12) * 8192;
    const ushort_t* Bbase = xpk + (size_t)(tt * 12) * 8192;
    int tid = threadIdx.x, lane = tid & 63, wave = tid >> 6;
    int wm = wave >> 1, wn = wave & 1;

    auto stage4 = [&](const ushort_t* src, ushort_t* dst) {
        const char* s = (const char*)src + wave * 4096 + lane * 16;
        char* l = (char*)dst + wave * 4096;
#pragma unroll
        for (int p = 0; p < 4; ++p)
            __builtin_amdgcn_global_load_lds((const glb_u32*)(s + p * 1024),
                                             (lds_u32*)(l + p * 1024), 16, 0, 0);
    };

    f32x16 acc[2][2];
#pragma unroll
    for (int mf = 0; mf < 2; ++mf)
#pragma unroll
        for (int nf = 0; nf < 2; ++nf)
#pragma unroll
            for (int r = 0; r < 16; ++r) acc[mf][nf][r] = 0.f;

    stage4(Abase, smem[0][0]);
    stage4(Bbase, smem[0][1]);

    for (int s = 0; s < 12; ++s) {
        int c = s & 1;
        bool more = (s + 1 < 12);
        if (more) {
            stage4(Abase + (s + 1) * 8192, smem[c ^ 1][0]);
            asm volatile("s_waitcnt vmcnt(4)" ::: "memory");
        } else {
            asm volatile("s_waitcnt vmcnt(0)" ::: "memory");
        }
        __builtin_amdgcn_s_barrier();
        __builtin_amdgcn_sched_barrier(0);

        const ushort_t* As = smem[c][0];
        const ushort_t* Bs = smem[c][1];
        short8 av0[2][2], bv0[2][2], av1[2][2], bv1[2][2];
        read_frags32(As, Bs, lane, wm, wn, 0, av0, bv0);
        asm volatile("s_waitcnt lgkmcnt(0)" ::: "memory");
        __builtin_amdgcn_sched_barrier(0);
        read_frags32(As, Bs, lane, wm, wn, 2, av1, bv1);
        if (more) stage4(Bbase + (s + 1) * 8192, smem[c ^ 1][1]);
        mfma32p(av0, bv0, acc);                     // overlaps av1/bv1 reads
        asm volatile("s_waitcnt lgkmcnt(0)" ::: "memory");
        __builtin_amdgcn_sched_barrier(0);
        mfma32p(av1, bv1, acc);
        __builtin_amdgcn_s_barrier();
    }

    // repack C tile (rows=e, cols=t) into packed image pair in LDS, stream out
    ushort_t* sm = &smem[0][0][0];
#pragma unroll
    for (int mf = 0; mf < 2; ++mf) {
#pragma unroll
        for (int nf = 0; nf < 2; ++nf) {
            int tcol = wn * 64 + nf * 32 + (lane & 31);
            int h = tcol >> 6, c6 = tcol & 63, sl = c6 >> 3, j = c6 & 7;
#pragma unroll
            for (int reg = 0; reg < 16; ++reg) {
                int erow = wm * 64 + mf * 32 + (reg & 3) + 8 * (reg >> 2) + 4 * (lane >> 5);
                sm[h * 8192 + erow * 64 + ((sl ^ (erow & 7)) << 3) + j] = f2bf(acc[mf][nf][reg]);
            }
        }
    }
    __syncthreads();
    uint4* d4 = (uint4*)(Apk + ((size_t)((kv * 6 + et) * 16 + tt) * 2) * 8192);
    const uint4* s4 = (const uint4*)sm;
#pragma unroll
    for (int p = 0; p < 8; ++p) d4[p * 256 + tid] = s4[p * 256 + tid];
}

// ---------------- stage B (r10 schedule, 32x32 MFMA) ----------------
// Work unit: (i1, et, zc), jj in {2zc, 2zc+1}; jj > i1 maps to T zero-slot (no-op).
// All 432 blocks identical NS = 192 -> kv-lockstep + no tail variance.
__global__ __launch_bounds__(256, 2)
void k_gemm_Bv4(const ushort_t* __restrict__ Tpk, const ushort_t* __restrict__ Apk,
                float* __restrict__ outz) {
    __shared__ ushort_t smem[2][2][8192];   // [buf][0=T, 1=A]

    int bid = blockIdx.x;                    // bijective XCD swizzle: 432 = 8*54
    int lid = (bid & 7) * 54 + (bid >> 3);
    int et = lid / 72;
    int cidx = lid % 72;
    int i1 = 0, zc = 0, base = 0;
#pragma unroll
    for (int t = 0; t < 16; ++t) {
        int cand = 15 - t;
        int nc = (cand >> 1) + 1;
        if (cidx < base + nc) { i1 = cand; zc = cidx - base; break; }
        base += nc;
    }
    int jlo = zc * 2;
    const int NS = NKV * 2 * 2;              // 48 kv * 2 jj * 2 halves, uniform

    int tid = threadIdx.x, lane = tid & 63, wave = tid >> 6;
    int wm = wave >> 1, wn = wave & 1;

    f32x16 acc[2][2];
#pragma unroll
    for (int mf = 0; mf < 2; ++mf)
#pragma unroll
        for (int nf = 0; nf < 2; ++nf)
#pragma unroll
            for (int r = 0; r < 16; ++r) acc[mf][nf][r] = 0.f;

    // T slot for (i1, jj): i1 - jj + 1; jj = i1+1 (padding) -> slot 0 = zeros
    auto timg = [&](int kv, int jj, int h) -> const ushort_t* {
        return Tpk + ((size_t)((kv * 17 + (i1 - jj + 1)) * 2 + h)) * 8192;
    };
    auto aimg = [&](int kv, int jj, int h) -> const ushort_t* {
        return Apk + ((size_t)(((kv * 6 + et) * 16 + jj) * 2 + h)) * 8192;
    };
    auto stage4 = [&](const ushort_t* src, ushort_t* dst) {
        const char* s = (const char*)src + wave * 4096 + lane * 16;
        char* l = (char*)dst + wave * 4096;
#pragma unroll
        for (int p = 0; p < 4; ++p)
            __builtin_amdgcn_global_load_lds((const glb_u32*)(s + p * 1024),
                                             (lds_u32*)(l + p * 1024), 16, 0, 0);
    };

    int kv = 0, jj = jlo, h = 0;
    stage4(timg(kv, jj, h), smem[0][0]);
    stage4(aimg(kv, jj, h), smem[0][1]);

    for (int s = 0; s < NS; ++s) {
        int c = s & 1;
        int nh = h ^ 1, njj = jj, nkvv = kv;
        if (!nh) { njj = jj + 1; if (njj > jlo + 1) { njj = jlo; nkvv = kv + 1; } }
        bool more = (s + 1 < NS);

        if (more) {
            stage4(timg(nkvv, njj, nh), smem[c ^ 1][0]);
            asm volatile("s_waitcnt vmcnt(4)" ::: "memory");   // this step's 8 landed
        } else {
            asm volatile("s_waitcnt vmcnt(0)" ::: "memory");
        }
        __builtin_amdgcn_s_barrier();
        __builtin_amdgcn_sched_barrier(0);

        const ushort_t* As = smem[c][0];
        const ushort_t* Bs = smem[c][1];
        short8 av0[2][2], bv0[2][2], av1[2][2], bv1[2][2];
        read_frags32(As, Bs, lane, wm, wn, 0, av0, bv0);
        read_frags32(As, Bs, lane, wm, wn, 2, av1, bv1);
        if (more) stage4(aimg(nkvv, njj, nh), smem[c ^ 1][1]);

        asm volatile("s_waitcnt lgkmcnt(0)" ::: "memory");
        __builtin_amdgcn_sched_barrier(0);

        mfma32p(av0, bv0, acc);
        mfma32p(av1, bv1, acc);
        __builtin_amdgcn_s_barrier();
        kv = nkvv; jj = njj; h = nh;
    }

    float* dst = outz + ((size_t)zc * SEQ + (size_t)i1 * 128) * DDIM + et * 128;
#pragma unroll
    for (int mf = 0; mf < 2; ++mf) {
#pragma unroll
        for (int nf = 0; nf < 2; ++nf) {
            int ecol = wn * 64 + nf * 32 + (lane & 31);
#pragma unroll
            for (int reg = 0; reg < 16; ++reg) {
                int srow = wm * 64 + mf * 32 + (reg & 3) + 8 * (reg >> 2) + 4 * (lane >> 5);
                dst[(size_t)srow * DDIM + ecol] = acc[mf][nf][reg];
            }
        }
    }
}

// sum only z-slices that were written for this row: zc <= srow>>8
__global__ void k_reduce(const float* __restrict__ outz, float* __restrict__ out, int n4) {
    int idx = blockIdx.x * blockDim.x + threadIdx.x;
    if (idx < n4) {
        int srow = idx / (DDIM / 4);
        int zmax = srow >> 8;
        if (zmax > NZC - 1) zmax = NZC - 1;
        float4 s = ((const float4*)outz)[idx];
        for (int z = 1; z <= zmax; ++z) {
            float4 t = ((const float4*)(outz + (size_t)z * SEQ * DDIM))[idx];
            s.x += t.x; s.y += t.y; s.z += t.z; s.w += t.w;
        }
        ((float4*)out)[idx] = s;
    }
}

extern "C" void kernel_launch(void* const* d_in, const int* in_sizes, int n_in,
                              void* d_out, int out_size, void* d_ws, size_t ws_size,
                              hipStream_t stream) {
    (void)in_sizes; (void)n_in;
    const float* x   = (const float*)d_in[0];
    const float* phi = (const float*)d_in[1];
    const float* Mp  = (const float*)d_in[2];
    const float* Mm  = (const float*)d_in[3];
    float* out = (float*)d_out;

    char* ws = (char*)d_ws;
    size_t off = 0;
    auto alloc = [&](size_t bytes) { size_t o = off; off += (bytes + 255) & ~(size_t)255; return o; };
    size_t o_xpk = alloc((size_t)16 * 12 * 8192 * 2);                // 3.0 MB
    size_t o_Mpk = alloc((size_t)NKV * 6 * 12 * 8192 * 2);           // 56.6 MB (aliased by outz)
    size_t o_Tpk = alloc((size_t)NKV * 17 * 2 * 8192 * 2);           // 26.8 MB
    size_t o_Apk = alloc((size_t)NKV * 6 * 16 * 2 * 8192 * 2);       // 151.0 MB
    if (off > ws_size) {   // should never happen (~237 MB total; r9/r10 proved fits)
        hipMemsetAsync(d_out, 0, (size_t)out_size * 4, stream);
        return;
    }

    ushort_t* xpk = (ushort_t*)(ws + o_xpk);
    ushort_t* Mpk = (ushort_t*)(ws + o_Mpk);
    ushort_t* Tpk = (ushort_t*)(ws + o_Tpk);
    ushort_t* Apk = (ushort_t*)(ws + o_Apk);
    float*   outz = (float*)(ws + o_Mpk);   // alias: Mpk dead after gemm_A; 50.3 <= 56.6 MB

    k_pack_x<<<16 * 12, 256, 0, stream>>>(x, xpk);
    k_pack_M<<<NKV * 6 * 12, 256, 0, stream>>>(Mp, Mm, Mpk);
    k_build_T<<<NKV * 17, 256, 0, stream>>>(phi, Tpk);
    k_gemm_A<<<NKV * 96, 256, 0, stream>>>(Mpk, xpk, Apk);
    k_gemm_Bv4<<<432, 256, 0, stream>>>(Tpk, Apk, outz);
    int n4 = SEQ * DDIM / 4;
    k_reduce<<<(n4 + 255) / 256, 256, 0, stream>>>(outz, out, n4);
}

// Round 13
// 332.310 us; speedup vs baseline: 1.5145x; 1.1410x over previous
//
#include <hip/hip_runtime.h>
#include <hip/hip_bf16.h>
#include <stdint.h>

#define SEQ 2048
#define DDIM 768
#define KF 24
#define NKV 48
#define NZC 8   // outz slices, zc = jj & 7

typedef unsigned short ushort_t;
typedef __attribute__((ext_vector_type(8))) short short8;
typedef __attribute__((ext_vector_type(4))) float f32x4;

typedef __attribute__((address_space(3))) uint32_t lds_u32;
typedef __attribute__((address_space(1))) uint32_t glb_u32;

__device__ __forceinline__ unsigned short f2bf(float f) {
    union { float f; uint32_t u; } v; v.f = f;
    uint32_t u = v.u;
    return (unsigned short)((u + 0x7fff + ((u >> 16) & 1)) >> 16);
}

// Image layout for a [128 rows][64 k] bf16 slab (16 KB), XOR-swizzled:
//   idx(row,k) = row*64 + (((k>>3) ^ (row&7))<<3) + (k&7)

// ---------------- prep: pack x ----------------
__global__ void k_pack_x(const float* __restrict__ x, ushort_t* __restrict__ xpk) {
    int b = blockIdx.x;            // tt*12 + ks
    int tt = b / 12, ks = b % 12;
    int tid = threadIdx.x;
    ushort_t* dst = xpk + (size_t)b * 8192;
    const float* src = x + (size_t)tt * 128 * DDIM + ks * 64;
#pragma unroll
    for (int p = 0; p < 4; ++p) {
        int s = p * 256 + tid;
        int row = s >> 3, sl = s & 7;
        const float* rp = src + (size_t)row * DDIM + sl * 8;
        float4 a = *(const float4*)rp;
        float4 c = *(const float4*)(rp + 4);
        ushort_t v[8] = {f2bf(a.x), f2bf(a.y), f2bf(a.z), f2bf(a.w),
                         f2bf(c.x), f2bf(c.y), f2bf(c.z), f2bf(c.w)};
        *(uint4*)(dst + row * 64 + ((sl ^ (row & 7)) << 3)) = *(uint4*)v;
    }
}

// ---------------- prep: pack M transposed ----------------
__global__ void k_pack_M(const float* __restrict__ Mp, const float* __restrict__ Mm,
                         ushort_t* __restrict__ Mpk) {
    __shared__ ushort_t lt[128 * 66];
    int b = blockIdx.x;            // (kv*6 + et)*12 + ks
    int kv = b / 72; int rem = b % 72; int et = rem / 12, ks = rem % 12;
    const float* src = ((kv < KF) ? Mp + (size_t)kv * DDIM * DDIM
                                  : Mm + (size_t)(kv - KF) * DDIM * DDIM)
                       + (size_t)(ks * 64) * DDIM + et * 128;
    int tid = threadIdx.x;
#pragma unroll
    for (int p = 0; p < 32; ++p) {
        int lin = p * 256 + tid;
        int d = lin >> 7, e = lin & 127;
        lt[e * 66 + d] = f2bf(src[(size_t)d * DDIM + e]);
    }
    __syncthreads();
    ushort_t* dst = Mpk + (size_t)b * 8192;
#pragma unroll
    for (int p = 0; p < 4; ++p) {
        int s = p * 256 + tid; int row = s >> 3, sl = s & 7;
        ushort_t v[8];
#pragma unroll
        for (int j = 0; j < 8; ++j) v[j] = lt[row * 66 + sl * 8 + j];
        *(uint4*)(dst + row * 64 + ((sl ^ (row & 7)) << 3)) = *(uint4*)v;
    }
}

// ---------------- prep: build Toeplitz blocks (17 lag slots, slot 0 = zeros) ----------------
__global__ void k_build_T(const float* __restrict__ phi, ushort_t* __restrict__ Tpk) {
    __shared__ float phiL[256];
    int b = blockIdx.x;            // kv*17 + slot
    int kv = b / 17, slot = b % 17;
    int dm = slot - 1;             // lag block; dm = -1 -> all zeros
    int k = kv % KF; bool neg = kv >= KF;
    int tid = threadIdx.x;
    int tau = 128 * dm - 127 + tid;
    float v = 0.f;
    if (tid < 255 && tau >= 0 && tau < SEQ) {
        v = phi[(size_t)tau * KF + k];
        if (neg && (tau & 1)) v = -v;
    }
    phiL[tid] = v;
    __syncthreads();
    ushort_t* dst = Tpk + (size_t)b * 2 * 8192;
#pragma unroll
    for (int h = 0; h < 2; ++h) {
#pragma unroll
        for (int p = 0; p < 4; ++p) {
            int s = p * 256 + tid; int row = s >> 3, sl = s & 7;
            ushort_t v8[8];
#pragma unroll
            for (int j = 0; j < 8; ++j) {
                int col = h * 64 + sl * 8 + j;
                v8[j] = f2bf(phiL[row - col + 127]);
            }
            *(uint4*)(dst + h * 8192 + row * 64 + ((sl ^ (row & 7)) << 3)) = *(uint4*)v8;
        }
    }
}

// ---------------- shared fragment-read helpers ----------------

__device__ __forceinline__ void read_frags(const ushort_t* As, const ushort_t* Bs,
                                           int lane, int wm, int wn, int kk,
                                           short8 av[4], short8 bv[4]) {
    int slot = kk * 4 + (lane >> 4);
#pragma unroll
    for (int m = 0; m < 4; ++m) {
        int row = wm * 64 + m * 16 + (lane & 15);
        av[m] = *(const short8*)(As + row * 64 + ((slot ^ (row & 7)) << 3));
    }
#pragma unroll
    for (int n = 0; n < 4; ++n) {
        int row = wn * 64 + n * 16 + (lane & 15);
        bv[n] = *(const short8*)(Bs + row * 64 + ((slot ^ (row & 7)) << 3));
    }
}

__device__ __forceinline__ void mfma16(const short8 av[4], const short8 bv[4], f32x4 acc[4][4]) {
    __builtin_amdgcn_s_setprio(1);
#pragma unroll
    for (int m = 0; m < 4; ++m)
#pragma unroll
        for (int n = 0; n < 4; ++n)
            acc[m][n] = __builtin_amdgcn_mfma_f32_16x16x32_bf16(av[m], bv[n], acc[m][n], 0, 0, 0);
    __builtin_amdgcn_s_setprio(0);
}

// ---------------- stage A (r10 exact): Apk[kv][et][tt][h][img] ----------------
__global__ __launch_bounds__(256, 2)
void k_gemm_A(const ushort_t* __restrict__ Mpk, const ushort_t* __restrict__ xpk,
              ushort_t* __restrict__ Apk) {
    __shared__ ushort_t smem[2][2][8192];
    int bid = blockIdx.x;
    int kv = bid / 96; int rem = bid % 96; int et = rem / 16, tt = rem % 16;
    const ushort_t* Abase = Mpk + ((size_t)(kv * 6 + et) * 12) * 8192;
    const ushort_t* Bbase = xpk + (size_t)(tt * 12) * 8192;
    int tid = threadIdx.x, lane = tid & 63, wave = tid >> 6;
    int wm = wave >> 1, wn = wave & 1;

    auto stage4 = [&](const ushort_t* src, ushort_t* dst) {
        const char* s = (const char*)src + wave * 4096 + lane * 16;
        char* l = (char*)dst + wave * 4096;
#pragma unroll
        for (int p = 0; p < 4; ++p)
            __builtin_amdgcn_global_load_lds((const glb_u32*)(s + p * 1024),
                                             (lds_u32*)(l + p * 1024), 16, 0, 0);
    };

    f32x4 acc[4][4];
#pragma unroll
    for (int m = 0; m < 4; ++m)
#pragma unroll
        for (int n = 0; n < 4; ++n) acc[m][n] = (f32x4){0.f, 0.f, 0.f, 0.f};

    stage4(Abase, smem[0][0]);
    stage4(Bbase, smem[0][1]);

    for (int s = 0; s < 12; ++s) {
        int c = s & 1;
        bool more = (s + 1 < 12);
        if (more) {
            stage4(Abase + (s + 1) * 8192, smem[c ^ 1][0]);
            asm volatile("s_waitcnt vmcnt(4)" ::: "memory");
        } else {
            asm volatile("s_waitcnt vmcnt(0)" ::: "memory");
        }
        __builtin_amdgcn_s_barrier();
        __builtin_amdgcn_sched_barrier(0);

        const ushort_t* As = smem[c][0];
        const ushort_t* Bs = smem[c][1];
        short8 av0[4], bv0[4], av1[4], bv1[4];
        read_frags(As, Bs, lane, wm, wn, 0, av0, bv0);
        asm volatile("s_waitcnt lgkmcnt(0)" ::: "memory");
        __builtin_amdgcn_sched_barrier(0);
        read_frags(As, Bs, lane, wm, wn, 1, av1, bv1);
        if (more) stage4(Bbase + (s + 1) * 8192, smem[c ^ 1][1]);
        mfma16(av0, bv0, acc);
        asm volatile("s_waitcnt lgkmcnt(0)" ::: "memory");
        __builtin_amdgcn_sched_barrier(0);
        mfma16(av1, bv1, acc);
        __builtin_amdgcn_s_barrier();
    }

    ushort_t* sm = &smem[0][0][0];
#pragma unroll
    for (int m = 0; m < 4; ++m) {
        int rb = wm * 64 + m * 16 + ((lane >> 4) << 2);
#pragma unroll
        for (int n = 0; n < 4; ++n) {
            int cb = wn * 64 + n * 16 + (lane & 15);
            int h = cb >> 6, c6 = cb & 63, sl = c6 >> 3, j = c6 & 7;
#pragma unroll
            for (int r = 0; r < 4; ++r) {
                int row = rb + r;
                sm[h * 8192 + row * 64 + ((sl ^ (row & 7)) << 3) + j] = f2bf(acc[m][n][r]);
            }
        }
    }
    __syncthreads();
    uint4* d4 = (uint4*)(Apk + ((size_t)((kv * 6 + et) * 16 + tt) * 2) * 8192);
    const uint4* s4 = (const uint4*)sm;
#pragma unroll
    for (int p = 0; p < 8; ++p) d4[p * 256 + tid] = s4[p * 256 + tid];
}

// ---------------- stage B v5: mixed-size units, heavy-first, slice zc = jj&7 ----------------
// Heavy unit (bid 0..215): (et, i1>=8, zc<=i1-8), jj in {zc, zc+8}, NS=192.
// Light unit (bid 216..599): single jj = zc, NS=96.
// 600 blocks = 816 jj-sweeps, zero padding; each (i1,et,zc) written by one block.
__global__ __launch_bounds__(256, 2)
void k_gemm_Bv5(const ushort_t* __restrict__ Tpk, const ushort_t* __restrict__ Apk,
                float* __restrict__ outz) {
    __shared__ ushort_t smem[2][2][8192];   // [buf][0=T, 1=A]

    int bid = blockIdx.x;
    int et, i1, zc, nj;
    if (bid < 216) {                          // heavy; XCD swizzle 216 = 8*27
        int l = (bid & 7) * 27 + (bid >> 3);
        et = l / 36; int r = l % 36;
        int u = 0;
#pragma unroll
        for (int t = 1; t < 8; ++t) if (r >= t * (t + 1) / 2) u = t;
        zc = r - u * (u + 1) / 2;
        i1 = u + 8; nj = 2;
    } else {                                  // light; XCD swizzle 384 = 8*48
        int b2 = bid - 216;
        int l = (b2 & 7) * 48 + (b2 >> 3);
        et = l / 64; int r = l % 64;
        if (r < 36) {                         // i1 <= 7 triangular
            int u = 0;
#pragma unroll
            for (int t = 1; t < 8; ++t) if (r >= t * (t + 1) / 2) u = t;
            i1 = u; zc = r - u * (u + 1) / 2;
        } else {                              // i1 >= 8 singles: zc in [i1-7, 7]
            int r2 = r - 36;
            int v = 0;
#pragma unroll
            for (int t = 1; t <= 6; ++t) { int pf = 7 * t - t * (t - 1) / 2; if (r2 >= pf) v = t; }
            i1 = 8 + v;
            zc = (v + 1) + (r2 - (7 * v - v * (v - 1) / 2));
        }
        nj = 1;
    }
    const int NS = 96 * nj;

    int tid = threadIdx.x, lane = tid & 63, wave = tid >> 6;
    int wm = wave >> 1, wn = wave & 1;

    f32x4 acc[4][4];
#pragma unroll
    for (int m = 0; m < 4; ++m)
#pragma unroll
        for (int n = 0; n < 4; ++n) acc[m][n] = (f32x4){0.f, 0.f, 0.f, 0.f};

    // step s -> (kv, jj, h); kv-outer, jj inner (alternates for nj=2)
    auto coords = [&](int s, int& kv, int& jj, int& h) {
        h = s & 1; int t = s >> 1;
        if (nj == 2) { jj = (t & 1) ? zc + 8 : zc; kv = t >> 1; }
        else { jj = zc; kv = t; }
    };
    auto timg = [&](int kv, int jj, int h) -> const ushort_t* {
        return Tpk + ((size_t)((kv * 17 + (i1 - jj + 1)) * 2 + h)) * 8192;
    };
    auto aimg = [&](int kv, int jj, int h) -> const ushort_t* {
        return Apk + ((size_t)(((kv * 6 + et) * 16 + jj) * 2 + h)) * 8192;
    };
    auto stage4 = [&](const ushort_t* src, ushort_t* dst) {
        const char* s = (const char*)src + wave * 4096 + lane * 16;
        char* l = (char*)dst + wave * 4096;
#pragma unroll
        for (int p = 0; p < 4; ++p)
            __builtin_amdgcn_global_load_lds((const glb_u32*)(s + p * 1024),
                                             (lds_u32*)(l + p * 1024), 16, 0, 0);
    };

    int kv, jj, h;
    coords(0, kv, jj, h);
    stage4(timg(kv, jj, h), smem[0][0]);
    stage4(aimg(kv, jj, h), smem[0][1]);

    for (int s = 0; s < NS; ++s) {
        int c = s & 1;
        bool more = (s + 1 < NS);
        int nkv, njj, nh;
        if (more) coords(s + 1, nkv, njj, nh); else { nkv = kv; njj = jj; nh = h; }

        if (more) {
            stage4(timg(nkv, njj, nh), smem[c ^ 1][0]);
            asm volatile("s_waitcnt vmcnt(4)" ::: "memory");   // this step's 8 landed
        } else {
            asm volatile("s_waitcnt vmcnt(0)" ::: "memory");
        }
        __builtin_amdgcn_s_barrier();
        __builtin_amdgcn_sched_barrier(0);

        const ushort_t* As = smem[c][0];
        const ushort_t* Bs = smem[c][1];
        short8 av[2][4], bv[2][4];
#pragma unroll
        for (int kk = 0; kk < 2; ++kk) {
            int slot = kk * 4 + (lane >> 4);
#pragma unroll
            for (int m = 0; m < 4; ++m) {
                int row = wm * 64 + m * 16 + (lane & 15);
                av[kk][m] = *(const short8*)(As + row * 64 + ((slot ^ (row & 7)) << 3));
            }
#pragma unroll
            for (int n = 0; n < 4; ++n) {
                int row = wn * 64 + n * 16 + (lane & 15);
                bv[kk][n] = *(const short8*)(Bs + row * 64 + ((slot ^ (row & 7)) << 3));
            }
        }
        if (more) stage4(aimg(nkv, njj, nh), smem[c ^ 1][1]);

        asm volatile("s_waitcnt lgkmcnt(0)" ::: "memory");
        __builtin_amdgcn_sched_barrier(0);

        __builtin_amdgcn_s_setprio(1);
#pragma unroll
        for (int kk = 0; kk < 2; ++kk)
#pragma unroll
            for (int m = 0; m < 4; ++m)
#pragma unroll
                for (int n = 0; n < 4; ++n)
                    acc[m][n] = __builtin_amdgcn_mfma_f32_16x16x32_bf16(av[kk][m], bv[kk][n], acc[m][n], 0, 0, 0);
        __builtin_amdgcn_s_setprio(0);
        __builtin_amdgcn_s_barrier();
        kv = nkv; jj = njj; h = nh;
    }

    float* dst = outz + ((size_t)zc * SEQ + (size_t)i1 * 128) * DDIM + et * 128;
#pragma unroll
    for (int m = 0; m < 4; ++m) {
        int rb = wm * 64 + m * 16 + ((lane >> 4) << 2);
#pragma unroll
        for (int n = 0; n < 4; ++n) {
            int cb = wn * 64 + n * 16 + (lane & 15);
#pragma unroll
            for (int r = 0; r < 4; ++r)
                dst[(size_t)(rb + r) * DDIM + cb] = acc[m][n][r];
        }
    }
}

// slices written for tile i1 = 0..min(i1,7); i1 = srow>>7
__global__ void k_reduce(const float* __restrict__ outz, float* __restrict__ out, int n4) {
    int idx = blockIdx.x * blockDim.x + threadIdx.x;
    if (idx < n4) {
        int srow = idx / (DDIM / 4);
        int zmax = srow >> 7;
        if (zmax > NZC - 1) zmax = NZC - 1;
        float4 s = ((const float4*)outz)[idx];
        for (int z = 1; z <= zmax; ++z) {
            float4 t = ((const float4*)(outz + (size_t)z * SEQ * DDIM))[idx];
            s.x += t.x; s.y += t.y; s.z += t.z; s.w += t.w;
        }
        ((float4*)out)[idx] = s;
    }
}

extern "C" void kernel_launch(void* const* d_in, const int* in_sizes, int n_in,
                              void* d_out, int out_size, void* d_ws, size_t ws_size,
                              hipStream_t stream) {
    (void)in_sizes; (void)n_in;
    const float* x   = (const float*)d_in[0];
    const float* phi = (const float*)d_in[1];
    const float* Mp  = (const float*)d_in[2];
    const float* Mm  = (const float*)d_in[3];
    float* out = (float*)d_out;

    char* ws = (char*)d_ws;
    size_t off = 0;
    auto alloc = [&](size_t bytes) { size_t o = off; off += (bytes + 255) & ~(size_t)255; return o; };
    size_t o_xpk = alloc((size_t)16 * 12 * 8192 * 2);                // 3.0 MB
    size_t o_Mpk = alloc((size_t)NKV * 6 * 12 * 8192 * 2);           // 56.6 MB (aliased by outz)
    size_t o_Tpk = alloc((size_t)NKV * 17 * 2 * 8192 * 2);           // 26.8 MB
    size_t o_Apk = alloc((size_t)NKV * 6 * 16 * 2 * 8192 * 2);       // 151.0 MB
    if (off > ws_size) {   // should never happen (~237 MB total; r9/r10 proved fits)
        hipMemsetAsync(d_out, 0, (size_t)out_size * 4, stream);
        return;
    }

    ushort_t* xpk = (ushort_t*)(ws + o_xpk);
    ushort_t* Mpk = (ushort_t*)(ws + o_Mpk);
    ushort_t* Tpk = (ushort_t*)(ws + o_Tpk);
    ushort_t* Apk = (ushort_t*)(ws + o_Apk);
    float*   outz = (float*)(ws + o_Mpk);   // alias: Mpk dead after gemm_A; 50.3 <= 56.6 MB

    k_pack_x<<<16 * 12, 256, 0, stream>>>(x, xpk);
    k_pack_M<<<NKV * 6 * 12, 256, 0, stream>>>(Mp, Mm, Mpk);
    k_build_T<<<NKV * 17, 256, 0, stream>>>(phi, Tpk);
    k_gemm_A<<<NKV * 96, 256, 0, stream>>>(Mpk, xpk, Apk);
    k_gemm_Bv5<<<600, 256, 0, stream>>>(Tpk, Apk, outz);
    int n4 = SEQ * DDIM / 4;
    k_reduce<<<(n4 + 255) / 256, 256, 0, stream>>>(outz, out, n4);
}

// Round 14
// 325.079 us; speedup vs baseline: 1.5482x; 1.0222x over previous
//
#include <hip/hip_runtime.h>
#include <hip/hip_bf16.h>
#include <stdint.h>

#define SEQ 2048
#define DDIM 768
#define KF 24
#define NKV 48
#define NZC 8   // outz split-K slices (jj-chunk of 2)

typedef unsigned short ushort_t;
typedef __attribute__((ext_vector_type(8))) short short8;
typedef __attribute__((ext_vector_type(4))) float f32x4;

typedef __attribute__((address_space(3))) uint32_t lds_u32;
typedef __attribute__((address_space(1))) uint32_t glb_u32;

__device__ __forceinline__ unsigned short f2bf(float f) {
    union { float f; uint32_t u; } v; v.f = f;
    uint32_t u = v.u;
    return (unsigned short)((u + 0x7fff + ((u >> 16) & 1)) >> 16);
}

// Image layout for a [128 rows][64 k] bf16 slab (16 KB), XOR-swizzled:
//   idx(row,k) = row*64 + (((k>>3) ^ (row&7))<<3) + (k&7)

// ---------------- prep: pack x ----------------
__global__ void k_pack_x(const float* __restrict__ x, ushort_t* __restrict__ xpk) {
    int b = blockIdx.x;            // tt*12 + ks
    int tt = b / 12, ks = b % 12;
    int tid = threadIdx.x;
    ushort_t* dst = xpk + (size_t)b * 8192;
    const float* src = x + (size_t)tt * 128 * DDIM + ks * 64;
#pragma unroll
    for (int p = 0; p < 4; ++p) {
        int s = p * 256 + tid;
        int row = s >> 3, sl = s & 7;
        const float* rp = src + (size_t)row * DDIM + sl * 8;
        float4 a = *(const float4*)rp;
        float4 c = *(const float4*)(rp + 4);
        ushort_t v[8] = {f2bf(a.x), f2bf(a.y), f2bf(a.z), f2bf(a.w),
                         f2bf(c.x), f2bf(c.y), f2bf(c.z), f2bf(c.w)};
        *(uint4*)(dst + row * 64 + ((sl ^ (row & 7)) << 3)) = *(uint4*)v;
    }
}

// ---------------- prep: pack M transposed ----------------
__global__ void k_pack_M(const float* __restrict__ Mp, const float* __restrict__ Mm,
                         ushort_t* __restrict__ Mpk) {
    __shared__ ushort_t lt[128 * 66];
    int b = blockIdx.x;            // (kv*6 + et)*12 + ks
    int kv = b / 72; int rem = b % 72; int et = rem / 12, ks = rem % 12;
    const float* src = ((kv < KF) ? Mp + (size_t)kv * DDIM * DDIM
                                  : Mm + (size_t)(kv - KF) * DDIM * DDIM)
                       + (size_t)(ks * 64) * DDIM + et * 128;
    int tid = threadIdx.x;
#pragma unroll
    for (int p = 0; p < 32; ++p) {
        int lin = p * 256 + tid;
        int d = lin >> 7, e = lin & 127;
        lt[e * 66 + d] = f2bf(src[(size_t)d * DDIM + e]);
    }
    __syncthreads();
    ushort_t* dst = Mpk + (size_t)b * 8192;
#pragma unroll
    for (int p = 0; p < 4; ++p) {
        int s = p * 256 + tid; int row = s >> 3, sl = s & 7;
        ushort_t v[8];
#pragma unroll
        for (int j = 0; j < 8; ++j) v[j] = lt[row * 66 + sl * 8 + j];
        *(uint4*)(dst + row * 64 + ((sl ^ (row & 7)) << 3)) = *(uint4*)v;
    }
}

// ---------------- prep: build Toeplitz blocks (17 lag slots, slot 0 = zeros) ----------------
__global__ void k_build_T(const float* __restrict__ phi, ushort_t* __restrict__ Tpk) {
    __shared__ float phiL[256];
    int b = blockIdx.x;            // kv*17 + slot
    int kv = b / 17, slot = b % 17;
    int dm = slot - 1;             // lag block; dm = -1 -> all zeros
    int k = kv % KF; bool neg = kv >= KF;
    int tid = threadIdx.x;
    int tau = 128 * dm - 127 + tid;
    float v = 0.f;
    if (tid < 255 && tau >= 0 && tau < SEQ) {
        v = phi[(size_t)tau * KF + k];
        if (neg && (tau & 1)) v = -v;
    }
    phiL[tid] = v;
    __syncthreads();
    ushort_t* dst = Tpk + (size_t)b * 2 * 8192;
#pragma unroll
    for (int h = 0; h < 2; ++h) {
#pragma unroll
        for (int p = 0; p < 4; ++p) {
            int s = p * 256 + tid; int row = s >> 3, sl = s & 7;
            ushort_t v8[8];
#pragma unroll
            for (int j = 0; j < 8; ++j) {
                int col = h * 64 + sl * 8 + j;
                v8[j] = f2bf(phiL[row - col + 127]);
            }
            *(uint4*)(dst + h * 8192 + row * 64 + ((sl ^ (row & 7)) << 3)) = *(uint4*)v8;
        }
    }
}

// ---------------- shared fragment-read helpers ----------------

__device__ __forceinline__ void read_frags(const ushort_t* As, const ushort_t* Bs,
                                           int lane, int wm, int wn, int kk,
                                           short8 av[4], short8 bv[4]) {
    int slot = kk * 4 + (lane >> 4);
#pragma unroll
    for (int m = 0; m < 4; ++m) {
        int row = wm * 64 + m * 16 + (lane & 15);
        av[m] = *(const short8*)(As + row * 64 + ((slot ^ (row & 7)) << 3));
    }
#pragma unroll
    for (int n = 0; n < 4; ++n) {
        int row = wn * 64 + n * 16 + (lane & 15);
        bv[n] = *(const short8*)(Bs + row * 64 + ((slot ^ (row & 7)) << 3));
    }
}

__device__ __forceinline__ void mfma16(const short8 av[4], const short8 bv[4], f32x4 acc[4][4]) {
    __builtin_amdgcn_s_setprio(1);
#pragma unroll
    for (int m = 0; m < 4; ++m)
#pragma unroll
        for (int n = 0; n < 4; ++n)
            acc[m][n] = __builtin_amdgcn_mfma_f32_16x16x32_bf16(av[m], bv[n], acc[m][n], 0, 0, 0);
    __builtin_amdgcn_s_setprio(0);
}

// ---------------- stage A v6: v4-style body + XCD kv-swizzle ----------------
// Apk[kv][et][tt][h][img] = (M_kv^T x^T) tile
__global__ __launch_bounds__(256, 2)
void k_gemm_A(const ushort_t* __restrict__ Mpk, const ushort_t* __restrict__ xpk,
              ushort_t* __restrict__ Apk) {
    __shared__ ushort_t smem[2][2][8192];
    int bid = blockIdx.x;
    int lid = (bid & 7) * 576 + (bid >> 3);   // bijective: XCD k owns kv in [6k, 6k+6)
    int kv = lid / 96; int rem = lid % 96; int et = rem / 16, tt = rem % 16;
    const ushort_t* Abase = Mpk + ((size_t)(kv * 6 + et) * 12) * 8192;
    const ushort_t* Bbase = xpk + (size_t)(tt * 12) * 8192;
    int tid = threadIdx.x, lane = tid & 63, wave = tid >> 6;
    int wm = wave >> 1, wn = wave & 1;

    auto stage4 = [&](const ushort_t* src, ushort_t* dst) {
        const char* s = (const char*)src + wave * 4096 + lane * 16;
        char* l = (char*)dst + wave * 4096;
#pragma unroll
        for (int p = 0; p < 4; ++p)
            __builtin_amdgcn_global_load_lds((const glb_u32*)(s + p * 1024),
                                             (lds_u32*)(l + p * 1024), 16, 0, 0);
    };

    f32x4 acc[4][4];
#pragma unroll
    for (int m = 0; m < 4; ++m)
#pragma unroll
        for (int n = 0; n < 4; ++n) acc[m][n] = (f32x4){0.f, 0.f, 0.f, 0.f};

    stage4(Abase, smem[0][0]);
    stage4(Bbase, smem[0][1]);

    for (int s = 0; s < 12; ++s) {
        int c = s & 1;
        bool more = (s + 1 < 12);
        if (more) {
            stage4(Abase + (s + 1) * 8192, smem[c ^ 1][0]);
            asm volatile("s_waitcnt vmcnt(4)" ::: "memory");   // this step's 8 landed
        } else {
            asm volatile("s_waitcnt vmcnt(0)" ::: "memory");
        }
        __builtin_amdgcn_s_barrier();
        __builtin_amdgcn_sched_barrier(0);

        const ushort_t* As = smem[c][0];
        const ushort_t* Bs = smem[c][1];
        short8 av[2][4], bv[2][4];
#pragma unroll
        for (int kk = 0; kk < 2; ++kk) {
            int slot = kk * 4 + (lane >> 4);
#pragma unroll
            for (int m = 0; m < 4; ++m) {
                int row = wm * 64 + m * 16 + (lane & 15);
                av[kk][m] = *(const short8*)(As + row * 64 + ((slot ^ (row & 7)) << 3));
            }
#pragma unroll
            for (int n = 0; n < 4; ++n) {
                int row = wn * 64 + n * 16 + (lane & 15);
                bv[kk][n] = *(const short8*)(Bs + row * 64 + ((slot ^ (row & 7)) << 3));
            }
        }
        if (more) stage4(Bbase + (s + 1) * 8192, smem[c ^ 1][1]);

        asm volatile("s_waitcnt lgkmcnt(0)" ::: "memory");
        __builtin_amdgcn_sched_barrier(0);

        __builtin_amdgcn_s_setprio(1);
#pragma unroll
        for (int kk = 0; kk < 2; ++kk)
#pragma unroll
            for (int m = 0; m < 4; ++m)
#pragma unroll
                for (int n = 0; n < 4; ++n)
                    acc[m][n] = __builtin_amdgcn_mfma_f32_16x16x32_bf16(av[kk][m], bv[kk][n], acc[m][n], 0, 0, 0);
        __builtin_amdgcn_s_setprio(0);
        __builtin_amdgcn_s_barrier();
    }

    // repack C tile (rows=e, cols=t) into packed image pair in LDS, stream out
    ushort_t* sm = &smem[0][0][0];
#pragma unroll
    for (int m = 0; m < 4; ++m) {
        int rb = wm * 64 + m * 16 + ((lane >> 4) << 2);
#pragma unroll
        for (int n = 0; n < 4; ++n) {
            int cb = wn * 64 + n * 16 + (lane & 15);
            int h = cb >> 6, c6 = cb & 63, sl = c6 >> 3, j = c6 & 7;
#pragma unroll
            for (int r = 0; r < 4; ++r) {
                int row = rb + r;
                sm[h * 8192 + row * 64 + ((sl ^ (row & 7)) << 3) + j] = f2bf(acc[m][n][r]);
            }
        }
    }
    __syncthreads();
    uint4* d4 = (uint4*)(Apk + ((size_t)((kv * 6 + et) * 16 + tt) * 2) * 8192);
    const uint4* s4 = (const uint4*)sm;
#pragma unroll
    for (int p = 0; p < 8; ++p) d4[p * 256 + tid] = s4[p * 256 + tid];
}

// ---------------- stage B (r10 exact: v4 body, uniform njj=2 via zero-slot) ----------------
// Work unit: (i1, et, zc), jj in {2zc, 2zc+1}; jj > i1 maps to T zero-slot (no-op).
// All 432 blocks identical NS = 192 -> kv-lockstep + no tail variance.
__global__ __launch_bounds__(256, 2)
void k_gemm_Bv4(const ushort_t* __restrict__ Tpk, const ushort_t* __restrict__ Apk,
                float* __restrict__ outz) {
    __shared__ ushort_t smem[2][2][8192];   // [buf][0=T, 1=A]

    int bid = blockIdx.x;                    // bijective XCD swizzle: 432 = 8*54
    int lid = (bid & 7) * 54 + (bid >> 3);
    int et = lid / 72;
    int cidx = lid % 72;
    int i1 = 0, zc = 0, base = 0;
#pragma unroll
    for (int t = 0; t < 16; ++t) {
        int cand = 15 - t;
        int nc = (cand >> 1) + 1;
        if (cidx < base + nc) { i1 = cand; zc = cidx - base; break; }
        base += nc;
    }
    int jlo = zc * 2;
    const int NS = NKV * 2 * 2;              // 48 kv * 2 jj * 2 halves, uniform

    int tid = threadIdx.x, lane = tid & 63, wave = tid >> 6;
    int wm = wave >> 1, wn = wave & 1;

    f32x4 acc[4][4];
#pragma unroll
    for (int m = 0; m < 4; ++m)
#pragma unroll
        for (int n = 0; n < 4; ++n) acc[m][n] = (f32x4){0.f, 0.f, 0.f, 0.f};

    // T slot for (i1, jj): i1 - jj + 1; jj = i1+1 (padding) -> slot 0 = zeros
    auto timg = [&](int kv, int jj, int h) -> const ushort_t* {
        return Tpk + ((size_t)((kv * 17 + (i1 - jj + 1)) * 2 + h)) * 8192;
    };
    auto aimg = [&](int kv, int jj, int h) -> const ushort_t* {
        return Apk + ((size_t)(((kv * 6 + et) * 16 + jj) * 2 + h)) * 8192;
    };
    auto stage4 = [&](const ushort_t* src, ushort_t* dst) {
        const char* s = (const char*)src + wave * 4096 + lane * 16;
        char* l = (char*)dst + wave * 4096;
#pragma unroll
        for (int p = 0; p < 4; ++p)
            __builtin_amdgcn_global_load_lds((const glb_u32*)(s + p * 1024),
                                             (lds_u32*)(l + p * 1024), 16, 0, 0);
    };

    int kv = 0, jj = jlo, h = 0;
    stage4(timg(kv, jj, h), smem[0][0]);
    stage4(aimg(kv, jj, h), smem[0][1]);

    for (int s = 0; s < NS; ++s) {
        int c = s & 1;
        int nh = h ^ 1, njj = jj, nkvv = kv;
        if (!nh) { njj = jj + 1; if (njj > jlo + 1) { njj = jlo; nkvv = kv + 1; } }
        bool more = (s + 1 < NS);

        if (more) {
            stage4(timg(nkvv, njj, nh), smem[c ^ 1][0]);
            asm volatile("s_waitcnt vmcnt(4)" ::: "memory");   // this step's 8 landed
        } else {
            asm volatile("s_waitcnt vmcnt(0)" ::: "memory");
        }
        __builtin_amdgcn_s_barrier();
        __builtin_amdgcn_sched_barrier(0);

        const ushort_t* As = smem[c][0];
        const ushort_t* Bs = smem[c][1];
        short8 av[2][4], bv[2][4];
#pragma unroll
        for (int kk = 0; kk < 2; ++kk) {
            int slot = kk * 4 + (lane >> 4);
#pragma unroll
            for (int m = 0; m < 4; ++m) {
                int row = wm * 64 + m * 16 + (lane & 15);
                av[kk][m] = *(const short8*)(As + row * 64 + ((slot ^ (row & 7)) << 3));
            }
#pragma unroll
            for (int n = 0; n < 4; ++n) {
                int row = wn * 64 + n * 16 + (lane & 15);
                bv[kk][n] = *(const short8*)(Bs + row * 64 + ((slot ^ (row & 7)) << 3));
            }
        }
        if (more) stage4(aimg(nkvv, njj, nh), smem[c ^ 1][1]);

        asm volatile("s_waitcnt lgkmcnt(0)" ::: "memory");
        __builtin_amdgcn_sched_barrier(0);

        __builtin_amdgcn_s_setprio(1);
#pragma unroll
        for (int kk = 0; kk < 2; ++kk)
#pragma unroll
            for (int m = 0; m < 4; ++m)
#pragma unroll
                for (int n = 0; n < 4; ++n)
                    acc[m][n] = __builtin_amdgcn_mfma_f32_16x16x32_bf16(av[kk][m], bv[kk][n], acc[m][n], 0, 0, 0);
        __builtin_amdgcn_s_setprio(0);
        __builtin_amdgcn_s_barrier();
        kv = nkvv; jj = njj; h = nh;
    }

    float* dst = outz + ((size_t)zc * SEQ + (size_t)i1 * 128) * DDIM + et * 128;
#pragma unroll
    for (int m = 0; m < 4; ++m) {
        int rb = wm * 64 + m * 16 + ((lane >> 4) << 2);
#pragma unroll
        for (int n = 0; n < 4; ++n) {
            int cb = wn * 64 + n * 16 + (lane & 15);
#pragma unroll
            for (int r = 0; r < 4; ++r)
                dst[(size_t)(rb + r) * DDIM + cb] = acc[m][n][r];
        }
    }
}

// sum only z-slices that were written for this row: zc <= srow>>8
__global__ void k_reduce(const float* __restrict__ outz, float* __restrict__ out, int n4) {
    int idx = blockIdx.x * blockDim.x + threadIdx.x;
    if (idx < n4) {
        int srow = idx / (DDIM / 4);
        int zmax = srow >> 8;
        if (zmax > NZC - 1) zmax = NZC - 1;
        float4 s = ((const float4*)outz)[idx];
        for (int z = 1; z <= zmax; ++z) {
            float4 t = ((const float4*)(outz + (size_t)z * SEQ * DDIM))[idx];
            s.x += t.x; s.y += t.y; s.z += t.z; s.w += t.w;
        }
        ((float4*)out)[idx] = s;
    }
}

extern "C" void kernel_launch(void* const* d_in, const int* in_sizes, int n_in,
                              void* d_out, int out_size, void* d_ws, size_t ws_size,
                              hipStream_t stream) {
    (void)in_sizes; (void)n_in;
    const float* x   = (const float*)d_in[0];
    const float* phi = (const float*)d_in[1];
    const float* Mp  = (const float*)d_in[2];
    const float* Mm  = (const float*)d_in[3];
    float* out = (float*)d_out;

    char* ws = (char*)d_ws;
    size_t off = 0;
    auto alloc = [&](size_t bytes) { size_t o = off; off += (bytes + 255) & ~(size_t)255; return o; };
    size_t o_xpk = alloc((size_t)16 * 12 * 8192 * 2);                // 3.0 MB
    size_t o_Mpk = alloc((size_t)NKV * 6 * 12 * 8192 * 2);           // 56.6 MB (aliased by outz)
    size_t o_Tpk = alloc((size_t)NKV * 17 * 2 * 8192 * 2);           // 26.8 MB
    size_t o_Apk = alloc((size_t)NKV * 6 * 16 * 2 * 8192 * 2);       // 151.0 MB
    if (off > ws_size) {   // should never happen (~237 MB total; r9/r10 proved fits)
        hipMemsetAsync(d_out, 0, (size_t)out_size * 4, stream);
        return;
    }

    ushort_t* xpk = (ushort_t*)(ws + o_xpk);
    ushort_t* Mpk = (ushort_t*)(ws + o_Mpk);
    ushort_t* Tpk = (ushort_t*)(ws + o_Tpk);
    ushort_t* Apk = (ushort_t*)(ws + o_Apk);
    float*   outz = (float*)(ws + o_Mpk);   // alias: Mpk dead after gemm_A; 50.3 <= 56.6 MB

    k_pack_x<<<16 * 12, 256, 0, stream>>>(x, xpk);
    k_pack_M<<<NKV * 6 * 12, 256, 0, stream>>>(Mp, Mm, Mpk);
    k_build_T<<<NKV * 17, 256, 0, stream>>>(phi, Tpk);
    k_gemm_A<<<NKV * 96, 256, 0, stream>>>(Mpk, xpk, Apk);
    k_gemm_Bv4<<<432, 256, 0, stream>>>(Tpk, Apk, outz);
    int n4 = SEQ * DDIM / 4;
    k_reduce<<<(n4 + 255) / 256, 256, 0, stream>>>(outz, out, n4);
}

// Round 15
// 309.782 us; speedup vs baseline: 1.6246x; 1.0494x over previous
//
#include <hip/hip_runtime.h>
#include <hip/hip_bf16.h>
#include <stdint.h>

#define SEQ 2048
#define DDIM 768
#define KF 24
#define NKV 48
#define NZC 8   // outz split-K slices (jj-chunk of 2)

typedef unsigned short ushort_t;
typedef __attribute__((ext_vector_type(8))) short short8;
typedef __attribute__((ext_vector_type(4))) float f32x4;

typedef __attribute__((address_space(3))) uint32_t lds_u32;
typedef __attribute__((address_space(1))) uint32_t glb_u32;

__device__ __forceinline__ unsigned short f2bf(float f) {
    union { float f; uint32_t u; } v; v.f = f;
    uint32_t u = v.u;
    return (unsigned short)((u + 0x7fff + ((u >> 16) & 1)) >> 16);
}

// Image layout for a [128 rows][64 k] bf16 slab (16 KB), XOR-swizzled:
//   idx(row,k) = row*64 + (((k>>3) ^ (row&7))<<3) + (k&7)

// ---------------- prep: pack x ----------------
__global__ void k_pack_x(const float* __restrict__ x, ushort_t* __restrict__ xpk) {
    int b = blockIdx.x;            // tt*12 + ks
    int tt = b / 12, ks = b % 12;
    int tid = threadIdx.x;
    ushort_t* dst = xpk + (size_t)b * 8192;
    const float* src = x + (size_t)tt * 128 * DDIM + ks * 64;
#pragma unroll
    for (int p = 0; p < 4; ++p) {
        int s = p * 256 + tid;
        int row = s >> 3, sl = s & 7;
        const float* rp = src + (size_t)row * DDIM + sl * 8;
        float4 a = *(const float4*)rp;
        float4 c = *(const float4*)(rp + 4);
        ushort_t v[8] = {f2bf(a.x), f2bf(a.y), f2bf(a.z), f2bf(a.w),
                         f2bf(c.x), f2bf(c.y), f2bf(c.z), f2bf(c.w)};
        *(uint4*)(dst + row * 64 + ((sl ^ (row & 7)) << 3)) = *(uint4*)v;
    }
}

// ---------------- prep: pack M transposed ----------------
__global__ void k_pack_M(const float* __restrict__ Mp, const float* __restrict__ Mm,
                         ushort_t* __restrict__ Mpk) {
    __shared__ ushort_t lt[128 * 66];
    int b = blockIdx.x;            // (kv*6 + et)*12 + ks
    int kv = b / 72; int rem = b % 72; int et = rem / 12, ks = rem % 12;
    const float* src = ((kv < KF) ? Mp + (size_t)kv * DDIM * DDIM
                                  : Mm + (size_t)(kv - KF) * DDIM * DDIM)
                       + (size_t)(ks * 64) * DDIM + et * 128;
    int tid = threadIdx.x;
#pragma unroll
    for (int p = 0; p < 32; ++p) {
        int lin = p * 256 + tid;
        int d = lin >> 7, e = lin & 127;
        lt[e * 66 + d] = f2bf(src[(size_t)d * DDIM + e]);
    }
    __syncthreads();
    ushort_t* dst = Mpk + (size_t)b * 8192;
#pragma unroll
    for (int p = 0; p < 4; ++p) {
        int s = p * 256 + tid; int row = s >> 3, sl = s & 7;
        ushort_t v[8];
#pragma unroll
        for (int j = 0; j < 8; ++j) v[j] = lt[row * 66 + sl * 8 + j];
        *(uint4*)(dst + row * 64 + ((sl ^ (row & 7)) << 3)) = *(uint4*)v;
    }
}

// ---------------- prep: build Toeplitz blocks — PLUS filters only (D-trick) ----------------
__global__ void k_build_T(const float* __restrict__ phi, ushort_t* __restrict__ Tpk) {
    __shared__ float phiL[256];
    int b = blockIdx.x;            // kv24*17 + slot
    int kv = b / 17, slot = b % 17;
    int dm = slot - 1;             // lag block; dm = -1 -> all zeros
    int tid = threadIdx.x;
    int tau = 128 * dm - 127 + tid;
    float v = 0.f;
    if (tid < 255 && tau >= 0 && tau < SEQ)
        v = phi[(size_t)tau * KF + kv];
    phiL[tid] = v;
    __syncthreads();
    ushort_t* dst = Tpk + (size_t)b * 2 * 8192;
#pragma unroll
    for (int h = 0; h < 2; ++h) {
#pragma unroll
        for (int p = 0; p < 4; ++p) {
            int s = p * 256 + tid; int row = s >> 3, sl = s & 7;
            ushort_t v8[8];
#pragma unroll
            for (int j = 0; j < 8; ++j) {
                int col = h * 64 + sl * 8 + j;
                v8[j] = f2bf(phiL[row - col + 127]);
            }
            *(uint4*)(dst + h * 8192 + row * 64 + ((sl ^ (row & 7)) << 3)) = *(uint4*)v8;
        }
    }
}

// ---------------- shared fragment-read helpers ----------------

__device__ __forceinline__ void read_frags(const ushort_t* As, const ushort_t* Bs,
                                           int lane, int wm, int wn, int kk,
                                           short8 av[4], short8 bv[4]) {
    int slot = kk * 4 + (lane >> 4);
#pragma unroll
    for (int m = 0; m < 4; ++m) {
        int row = wm * 64 + m * 16 + (lane & 15);
        av[m] = *(const short8*)(As + row * 64 + ((slot ^ (row & 7)) << 3));
    }
#pragma unroll
    for (int n = 0; n < 4; ++n) {
        int row = wn * 64 + n * 16 + (lane & 15);
        bv[n] = *(const short8*)(Bs + row * 64 + ((slot ^ (row & 7)) << 3));
    }
}

__device__ __forceinline__ void mfma16(const short8 av[4], const short8 bv[4], f32x4 acc[4][4]) {
    __builtin_amdgcn_s_setprio(1);
#pragma unroll
    for (int m = 0; m < 4; ++m)
#pragma unroll
        for (int n = 0; n < 4; ++n)
            acc[m][n] = __builtin_amdgcn_mfma_f32_16x16x32_bf16(av[m], bv[n], acc[m][n], 0, 0, 0);
    __builtin_amdgcn_s_setprio(0);
}

// ---------------- stage A (r14 body): Apk[kv][et][tt][h][img] ----------------
// For kv >= KF (minus branch), columns t are pre-scaled by (-1)^t (D-trick).
__global__ __launch_bounds__(256, 2)
void k_gemm_A(const ushort_t* __restrict__ Mpk, const ushort_t* __restrict__ xpk,
              ushort_t* __restrict__ Apk) {
    __shared__ ushort_t smem[2][2][8192];
    int bid = blockIdx.x;
    int lid = (bid & 7) * 576 + (bid >> 3);   // bijective: XCD k owns kv in [6k, 6k+6)
    int kv = lid / 96; int rem = lid % 96; int et = rem / 16, tt = rem % 16;
    const ushort_t* Abase = Mpk + ((size_t)(kv * 6 + et) * 12) * 8192;
    const ushort_t* Bbase = xpk + (size_t)(tt * 12) * 8192;
    int tid = threadIdx.x, lane = tid & 63, wave = tid >> 6;
    int wm = wave >> 1, wn = wave & 1;

    auto stage4 = [&](const ushort_t* src, ushort_t* dst) {
        const char* s = (const char*)src + wave * 4096 + lane * 16;
        char* l = (char*)dst + wave * 4096;
#pragma unroll
        for (int p = 0; p < 4; ++p)
            __builtin_amdgcn_global_load_lds((const glb_u32*)(s + p * 1024),
                                             (lds_u32*)(l + p * 1024), 16, 0, 0);
    };

    f32x4 acc[4][4];
#pragma unroll
    for (int m = 0; m < 4; ++m)
#pragma unroll
        for (int n = 0; n < 4; ++n) acc[m][n] = (f32x4){0.f, 0.f, 0.f, 0.f};

    stage4(Abase, smem[0][0]);
    stage4(Bbase, smem[0][1]);

    for (int s = 0; s < 12; ++s) {
        int c = s & 1;
        bool more = (s + 1 < 12);
        if (more) {
            stage4(Abase + (s + 1) * 8192, smem[c ^ 1][0]);
            asm volatile("s_waitcnt vmcnt(4)" ::: "memory");
        } else {
            asm volatile("s_waitcnt vmcnt(0)" ::: "memory");
        }
        __builtin_amdgcn_s_barrier();
        __builtin_amdgcn_sched_barrier(0);

        const ushort_t* As = smem[c][0];
        const ushort_t* Bs = smem[c][1];
        short8 av[2][4], bv[2][4];
#pragma unroll
        for (int kk = 0; kk < 2; ++kk) {
            int slot = kk * 4 + (lane >> 4);
#pragma unroll
            for (int m = 0; m < 4; ++m) {
                int row = wm * 64 + m * 16 + (lane & 15);
                av[kk][m] = *(const short8*)(As + row * 64 + ((slot ^ (row & 7)) << 3));
            }
#pragma unroll
            for (int n = 0; n < 4; ++n) {
                int row = wn * 64 + n * 16 + (lane & 15);
                bv[kk][n] = *(const short8*)(Bs + row * 64 + ((slot ^ (row & 7)) << 3));
            }
        }
        if (more) stage4(Bbase + (s + 1) * 8192, smem[c ^ 1][1]);

        asm volatile("s_waitcnt lgkmcnt(0)" ::: "memory");
        __builtin_amdgcn_sched_barrier(0);

        __builtin_amdgcn_s_setprio(1);
#pragma unroll
        for (int kk = 0; kk < 2; ++kk)
#pragma unroll
            for (int m = 0; m < 4; ++m)
#pragma unroll
                for (int n = 0; n < 4; ++n)
                    acc[m][n] = __builtin_amdgcn_mfma_f32_16x16x32_bf16(av[kk][m], bv[kk][n], acc[m][n], 0, 0, 0);
        __builtin_amdgcn_s_setprio(0);
        __builtin_amdgcn_s_barrier();
    }

    // repack C tile (rows=e, cols=t); minus branch pre-scaled by (-1)^t (t parity = lane&1)
    float fs = (kv >= KF && (lane & 1)) ? -1.f : 1.f;
    ushort_t* sm = &smem[0][0][0];
#pragma unroll
    for (int m = 0; m < 4; ++m) {
        int rb = wm * 64 + m * 16 + ((lane >> 4) << 2);
#pragma unroll
        for (int n = 0; n < 4; ++n) {
            int cb = wn * 64 + n * 16 + (lane & 15);
            int h = cb >> 6, c6 = cb & 63, sl = c6 >> 3, j = c6 & 7;
#pragma unroll
            for (int r = 0; r < 4; ++r) {
                int row = rb + r;
                sm[h * 8192 + row * 64 + ((sl ^ (row & 7)) << 3) + j] = f2bf(fs * acc[m][n][r]);
            }
        }
    }
    __syncthreads();
    uint4* d4 = (uint4*)(Apk + ((size_t)((kv * 6 + et) * 16 + tt) * 2) * 8192);
    const uint4* s4 = (const uint4*)sm;
#pragma unroll
    for (int p = 0; p < 8; ++p) d4[p * 256 + tid] = s4[p * 256 + tid];
}

// ---------------- stage B v6: D-trick (shared T, dual acc), (et,zc,i1) ordering ----------------
// Unit (et, zc, i1): jj in {2zc, 2zc+1}; kv24 in [0,24); sub-steps (jj, sign, h).
// sign=1 re-fetches the SAME T image (L2 hit) and accumulates into accm;
// out = accp + D*accm, D = diag((-1)^srow) -> reg-parity sign in epilogue.
__global__ __launch_bounds__(256, 2)
void k_gemm_Bv6(const ushort_t* __restrict__ Tpk, const ushort_t* __restrict__ Apk,
                float* __restrict__ outz) {
    __shared__ ushort_t smem[2][2][8192];   // [buf][0=T, 1=A]

    int bid = blockIdx.x;                    // bijective XCD swizzle: 432 = 8*54
    int lid = (bid & 7) * 54 + (bid >> 3);
    int et = lid / 72;
    int r = lid % 72;
    int zc = 0;                              // group prefix P(z) = z*(17-z)
#pragma unroll
    for (int z = 1; z < 8; ++z) if (r >= z * (17 - z)) zc = z;
    int i1 = 2 * zc + (r - zc * (17 - zc));
    int jlo = zc * 2;

    int tid = threadIdx.x, lane = tid & 63, wave = tid >> 6;
    int wm = wave >> 1, wn = wave & 1;

    f32x4 accp[4][4], accm[4][4];
#pragma unroll
    for (int m = 0; m < 4; ++m)
#pragma unroll
        for (int n = 0; n < 4; ++n) {
            accp[m][n] = (f32x4){0.f, 0.f, 0.f, 0.f};
            accm[m][n] = (f32x4){0.f, 0.f, 0.f, 0.f};
        }

    // T slot for (i1, jj): i1 - jj + 1; padded jj = i1+1 -> slot 0 = zeros
    auto timg = [&](int kv24, int jjs, int h) -> const ushort_t* {
        return Tpk + ((size_t)((kv24 * 17 + (i1 - (jlo + jjs) + 1)) * 2 + h)) * 8192;
    };
    auto aimg = [&](int kv24, int sign, int jjs, int h) -> const ushort_t* {
        return Apk + ((size_t)((((kv24 + KF * sign) * 6 + et) * 16 + (jlo + jjs)) * 2 + h)) * 8192;
    };
    auto stage4 = [&](const ushort_t* src, ushort_t* dst) {
        const char* s = (const char*)src + wave * 4096 + lane * 16;
        char* l = (char*)dst + wave * 4096;
#pragma unroll
        for (int p = 0; p < 4; ++p)
            __builtin_amdgcn_global_load_lds((const glb_u32*)(s + p * 1024),
                                             (lds_u32*)(l + p * 1024), 16, 0, 0);
    };

    // prologue: step (kv24=0, rem=0) into buf 0
    stage4(timg(0, 0, 0), smem[0][0]);
    stage4(aimg(0, 0, 0, 0), smem[0][1]);

    for (int kv24 = 0; kv24 < KF; ++kv24) {
#pragma unroll
        for (int rem = 0; rem < 8; ++rem) {           // rem = jjs*4 + sign*2 + h
            const int sign = (rem >> 1) & 1, h = rem & 1;
            const int c = h;                          // step parity == h
            const int nrem = (rem + 1) & 7;
            const int njjs = nrem >> 2, nsign = (nrem >> 1) & 1, nh = nrem & 1;
            int nkv = kv24 + (rem == 7);
            bool more = (nkv < KF);

            if (more) {
                stage4(timg(nkv, njjs, nh), smem[c ^ 1][0]);
                asm volatile("s_waitcnt vmcnt(4)" ::: "memory");   // this step's 8 landed
            } else {
                asm volatile("s_waitcnt vmcnt(0)" ::: "memory");
            }
            __builtin_amdgcn_s_barrier();
            __builtin_amdgcn_sched_barrier(0);

            const ushort_t* As = smem[c][0];
            const ushort_t* Bs = smem[c][1];
            short8 av[2][4], bv[2][4];
#pragma unroll
            for (int kk = 0; kk < 2; ++kk) {
                int slot = kk * 4 + (lane >> 4);
#pragma unroll
                for (int m = 0; m < 4; ++m) {
                    int row = wm * 64 + m * 16 + (lane & 15);
                    av[kk][m] = *(const short8*)(As + row * 64 + ((slot ^ (row & 7)) << 3));
                }
#pragma unroll
                for (int n = 0; n < 4; ++n) {
                    int row = wn * 64 + n * 16 + (lane & 15);
                    bv[kk][n] = *(const short8*)(Bs + row * 64 + ((slot ^ (row & 7)) << 3));
                }
            }
            if (more) stage4(aimg(nkv, nsign, njjs, nh), smem[c ^ 1][1]);

            asm volatile("s_waitcnt lgkmcnt(0)" ::: "memory");
            __builtin_amdgcn_sched_barrier(0);

            __builtin_amdgcn_s_setprio(1);
            if (sign == 0) {                          // static: rem unrolled
#pragma unroll
                for (int kk = 0; kk < 2; ++kk)
#pragma unroll
                    for (int m = 0; m < 4; ++m)
#pragma unroll
                        for (int n = 0; n < 4; ++n)
                            accp[m][n] = __builtin_amdgcn_mfma_f32_16x16x32_bf16(av[kk][m], bv[kk][n], accp[m][n], 0, 0, 0);
            } else {
#pragma unroll
                for (int kk = 0; kk < 2; ++kk)
#pragma unroll
                    for (int m = 0; m < 4; ++m)
#pragma unroll
                        for (int n = 0; n < 4; ++n)
                            accm[m][n] = __builtin_amdgcn_mfma_f32_16x16x32_bf16(av[kk][m], bv[kk][n], accm[m][n], 0, 0, 0);
            }
            __builtin_amdgcn_s_setprio(0);
            __builtin_amdgcn_s_barrier();
        }
    }

    // epilogue: out = accp + D*accm; row = rb + r4 (rb even) -> sign = (-1)^r4
    float* dst = outz + ((size_t)zc * SEQ + (size_t)i1 * 128) * DDIM + et * 128;
#pragma unroll
    for (int m = 0; m < 4; ++m) {
        int rb = wm * 64 + m * 16 + ((lane >> 4) << 2);
#pragma unroll
        for (int n = 0; n < 4; ++n) {
            int cb = wn * 64 + n * 16 + (lane & 15);
#pragma unroll
            for (int r4 = 0; r4 < 4; ++r4) {
                float vm = accm[m][n][r4];
                float v = accp[m][n][r4] + ((r4 & 1) ? -vm : vm);
                dst[(size_t)(rb + r4) * DDIM + cb] = v;
            }
        }
    }
}

// sum only z-slices that were written for this row: zc <= srow>>8
__global__ void k_reduce(const float* __restrict__ outz, float* __restrict__ out, int n4) {
    int idx = blockIdx.x * blockDim.x + threadIdx.x;
    if (idx < n4) {
        int srow = idx / (DDIM / 4);
        int zmax = srow >> 8;
        if (zmax > NZC - 1) zmax = NZC - 1;
        float4 s = ((const float4*)outz)[idx];
        for (int z = 1; z <= zmax; ++z) {
            float4 t = ((const float4*)(outz + (size_t)z * SEQ * DDIM))[idx];
            s.x += t.x; s.y += t.y; s.z += t.z; s.w += t.w;
        }
        ((float4*)out)[idx] = s;
    }
}

extern "C" void kernel_launch(void* const* d_in, const int* in_sizes, int n_in,
                              void* d_out, int out_size, void* d_ws, size_t ws_size,
                              hipStream_t stream) {
    (void)in_sizes; (void)n_in;
    const float* x   = (const float*)d_in[0];
    const float* phi = (const float*)d_in[1];
    const float* Mp  = (const float*)d_in[2];
    const float* Mm  = (const float*)d_in[3];
    float* out = (float*)d_out;

    char* ws = (char*)d_ws;
    size_t off = 0;
    auto alloc = [&](size_t bytes) { size_t o = off; off += (bytes + 255) & ~(size_t)255; return o; };
    size_t o_xpk = alloc((size_t)16 * 12 * 8192 * 2);                // 3.0 MB
    size_t o_Mpk = alloc((size_t)NKV * 6 * 12 * 8192 * 2);           // 56.6 MB (aliased by outz)
    size_t o_Tpk = alloc((size_t)KF * 17 * 2 * 8192 * 2);            // 13.4 MB (plus-only)
    size_t o_Apk = alloc((size_t)NKV * 6 * 16 * 2 * 8192 * 2);       // 151.0 MB
    if (off > ws_size) {   // should never happen (~224 MB total; r9-r14 proved >=237 fits)
        hipMemsetAsync(d_out, 0, (size_t)out_size * 4, stream);
        return;
    }

    ushort_t* xpk = (ushort_t*)(ws + o_xpk);
    ushort_t* Mpk = (ushort_t*)(ws + o_Mpk);
    ushort_t* Tpk = (ushort_t*)(ws + o_Tpk);
    ushort_t* Apk = (ushort_t*)(ws + o_Apk);
    float*   outz = (float*)(ws + o_Mpk);   // alias: Mpk dead after gemm_A; 50.3 <= 56.6 MB

    k_pack_x<<<16 * 12, 256, 0, stream>>>(x, xpk);
    k_pack_M<<<NKV * 6 * 12, 256, 0, stream>>>(Mp, Mm, Mpk);
    k_build_T<<<KF * 17, 256, 0, stream>>>(phi, Tpk);
    k_gemm_A<<<NKV * 96, 256, 0, stream>>>(Mpk, xpk, Apk);
    k_gemm_Bv6<<<432, 256, 0, stream>>>(Tpk, Apk, outz);
    int n4 = SEQ * DDIM / 4;
    k_reduce<<<(n4 + 255) / 256, 256, 0, stream>>>(outz, out, n4);
}

// Round 16
// 301.551 us; speedup vs baseline: 1.6689x; 1.0273x over previous
//
#include <hip/hip_runtime.h>
#include <hip/hip_bf16.h>
#include <stdint.h>

#define SEQ 2048
#define DDIM 768
#define KF 24
#define NKV 48
#define NZC 8   // outz split-K slices (jj-chunk of 2)

typedef unsigned short ushort_t;
typedef __attribute__((ext_vector_type(8))) short short8;
typedef __attribute__((ext_vector_type(4))) float f32x4;

typedef __attribute__((address_space(3))) uint32_t lds_u32;
typedef __attribute__((address_space(1))) uint32_t glb_u32;

__device__ __forceinline__ unsigned short f2bf(float f) {
    union { float f; uint32_t u; } v; v.f = f;
    uint32_t u = v.u;
    return (unsigned short)((u + 0x7fff + ((u >> 16) & 1)) >> 16);
}

// Image layout for a [128 rows][64 k] bf16 slab (16 KB), XOR-swizzled:
//   idx(row,k) = row*64 + (((k>>3) ^ (row&7))<<3) + (k&7)

// ---------------- fused prep: pack_x (192) + pack_M (3456) + build_T (408) ----------------
__global__ void k_prep(const float* __restrict__ x, const float* __restrict__ Mp,
                       const float* __restrict__ Mm, const float* __restrict__ phi,
                       ushort_t* __restrict__ xpk, ushort_t* __restrict__ Mpk,
                       ushort_t* __restrict__ Tpk) {
    __shared__ ushort_t lt[128 * 66];
    __shared__ float phiL[256];
    int b0 = blockIdx.x;
    int tid = threadIdx.x;

    if (b0 < 192) {                       // ---- pack_x: b = tt*12 + ks
        int b = b0;
        int tt = b / 12, ks = b % 12;
        ushort_t* dst = xpk + (size_t)b * 8192;
        const float* src = x + (size_t)tt * 128 * DDIM + ks * 64;
#pragma unroll
        for (int p = 0; p < 4; ++p) {
            int s = p * 256 + tid;
            int row = s >> 3, sl = s & 7;
            const float* rp = src + (size_t)row * DDIM + sl * 8;
            float4 a = *(const float4*)rp;
            float4 c = *(const float4*)(rp + 4);
            ushort_t v[8] = {f2bf(a.x), f2bf(a.y), f2bf(a.z), f2bf(a.w),
                             f2bf(c.x), f2bf(c.y), f2bf(c.z), f2bf(c.w)};
            *(uint4*)(dst + row * 64 + ((sl ^ (row & 7)) << 3)) = *(uint4*)v;
        }
    } else if (b0 < 192 + 3456) {         // ---- pack_M: b = (kv*6 + et)*12 + ks
        int b = b0 - 192;
        int kv = b / 72; int rem = b % 72; int et = rem / 12, ks = rem % 12;
        const float* src = ((kv < KF) ? Mp + (size_t)kv * DDIM * DDIM
                                      : Mm + (size_t)(kv - KF) * DDIM * DDIM)
                           + (size_t)(ks * 64) * DDIM + et * 128;
#pragma unroll
        for (int p = 0; p < 32; ++p) {
            int lin = p * 256 + tid;
            int d = lin >> 7, e = lin & 127;
            lt[e * 66 + d] = f2bf(src[(size_t)d * DDIM + e]);
        }
        __syncthreads();
        ushort_t* dst = Mpk + (size_t)b * 8192;
#pragma unroll
        for (int p = 0; p < 4; ++p) {
            int s = p * 256 + tid; int row = s >> 3, sl = s & 7;
            ushort_t v[8];
#pragma unroll
            for (int j = 0; j < 8; ++j) v[j] = lt[row * 66 + sl * 8 + j];
            *(uint4*)(dst + row * 64 + ((sl ^ (row & 7)) << 3)) = *(uint4*)v;
        }
    } else {                              // ---- build_T (plus filters only): b = kv24*17 + slot
        int b = b0 - (192 + 3456);
        int kv = b / 17, slot = b % 17;
        int dm = slot - 1;                // lag block; dm = -1 -> all zeros
        int tau = 128 * dm - 127 + tid;
        float v = 0.f;
        if (tid < 255 && tau >= 0 && tau < SEQ)
            v = phi[(size_t)tau * KF + kv];
        phiL[tid] = v;
        __syncthreads();
        ushort_t* dst = Tpk + (size_t)b * 2 * 8192;
#pragma unroll
        for (int h = 0; h < 2; ++h) {
#pragma unroll
            for (int p = 0; p < 4; ++p) {
                int s = p * 256 + tid; int row = s >> 3, sl = s & 7;
                ushort_t v8[8];
#pragma unroll
                for (int j = 0; j < 8; ++j) {
                    int col = h * 64 + sl * 8 + j;
                    v8[j] = f2bf(phiL[row - col + 127]);
                }
                *(uint4*)(dst + h * 8192 + row * 64 + ((sl ^ (row & 7)) << 3)) = *(uint4*)v8;
            }
        }
    }
}

// ---------------- shared fragment-read helpers ----------------

__device__ __forceinline__ void read_frags(const ushort_t* As, const ushort_t* Bs,
                                           int lane, int wm, int wn, int kk,
                                           short8 av[4], short8 bv[4]) {
    int slot = kk * 4 + (lane >> 4);
#pragma unroll
    for (int m = 0; m < 4; ++m) {
        int row = wm * 64 + m * 16 + (lane & 15);
        av[m] = *(const short8*)(As + row * 64 + ((slot ^ (row & 7)) << 3));
    }
#pragma unroll
    for (int n = 0; n < 4; ++n) {
        int row = wn * 64 + n * 16 + (lane & 15);
        bv[n] = *(const short8*)(Bs + row * 64 + ((slot ^ (row & 7)) << 3));
    }
}

// ---------------- stage A (r15 exact): Apk[kv][et][tt][h][img] ----------------
// For kv >= KF (minus branch), columns t are pre-scaled by (-1)^t (D-trick).
__global__ __launch_bounds__(256, 2)
void k_gemm_A(const ushort_t* __restrict__ Mpk, const ushort_t* __restrict__ xpk,
              ushort_t* __restrict__ Apk) {
    __shared__ ushort_t smem[2][2][8192];
    int bid = blockIdx.x;
    int lid = (bid & 7) * 576 + (bid >> 3);   // bijective: XCD k owns kv in [6k, 6k+6)
    int kv = lid / 96; int rem = lid % 96; int et = rem / 16, tt = rem % 16;
    const ushort_t* Abase = Mpk + ((size_t)(kv * 6 + et) * 12) * 8192;
    const ushort_t* Bbase = xpk + (size_t)(tt * 12) * 8192;
    int tid = threadIdx.x, lane = tid & 63, wave = tid >> 6;
    int wm = wave >> 1, wn = wave & 1;

    auto stage4 = [&](const ushort_t* src, ushort_t* dst) {
        const char* s = (const char*)src + wave * 4096 + lane * 16;
        char* l = (char*)dst + wave * 4096;
#pragma unroll
        for (int p = 0; p < 4; ++p)
            __builtin_amdgcn_global_load_lds((const glb_u32*)(s + p * 1024),
                                             (lds_u32*)(l + p * 1024), 16, 0, 0);
    };

    f32x4 acc[4][4];
#pragma unroll
    for (int m = 0; m < 4; ++m)
#pragma unroll
        for (int n = 0; n < 4; ++n) acc[m][n] = (f32x4){0.f, 0.f, 0.f, 0.f};

    stage4(Abase, smem[0][0]);
    stage4(Bbase, smem[0][1]);

    for (int s = 0; s < 12; ++s) {
        int c = s & 1;
        bool more = (s + 1 < 12);
        if (more) {
            stage4(Abase + (s + 1) * 8192, smem[c ^ 1][0]);
            asm volatile("s_waitcnt vmcnt(4)" ::: "memory");
        } else {
            asm volatile("s_waitcnt vmcnt(0)" ::: "memory");
        }
        __builtin_amdgcn_s_barrier();
        __builtin_amdgcn_sched_barrier(0);

        const ushort_t* As = smem[c][0];
        const ushort_t* Bs = smem[c][1];
        short8 av[2][4], bv[2][4];
#pragma unroll
        for (int kk = 0; kk < 2; ++kk) {
            int slot = kk * 4 + (lane >> 4);
#pragma unroll
            for (int m = 0; m < 4; ++m) {
                int row = wm * 64 + m * 16 + (lane & 15);
                av[kk][m] = *(const short8*)(As + row * 64 + ((slot ^ (row & 7)) << 3));
            }
#pragma unroll
            for (int n = 0; n < 4; ++n) {
                int row = wn * 64 + n * 16 + (lane & 15);
                bv[kk][n] = *(const short8*)(Bs + row * 64 + ((slot ^ (row & 7)) << 3));
            }
        }
        if (more) stage4(Bbase + (s + 1) * 8192, smem[c ^ 1][1]);

        asm volatile("s_waitcnt lgkmcnt(0)" ::: "memory");
        __builtin_amdgcn_sched_barrier(0);

        __builtin_amdgcn_s_setprio(1);
#pragma unroll
        for (int kk = 0; kk < 2; ++kk)
#pragma unroll
            for (int m = 0; m < 4; ++m)
#pragma unroll
                for (int n = 0; n < 4; ++n)
                    acc[m][n] = __builtin_amdgcn_mfma_f32_16x16x32_bf16(av[kk][m], bv[kk][n], acc[m][n], 0, 0, 0);
        __builtin_amdgcn_s_setprio(0);
        __builtin_amdgcn_s_barrier();
    }

    // repack C tile (rows=e, cols=t); minus branch pre-scaled by (-1)^t (t parity = lane&1)
    float fs = (kv >= KF && (lane & 1)) ? -1.f : 1.f;
    ushort_t* sm = &smem[0][0][0];
#pragma unroll
    for (int m = 0; m < 4; ++m) {
        int rb = wm * 64 + m * 16 + ((lane >> 4) << 2);
#pragma unroll
        for (int n = 0; n < 4; ++n) {
            int cb = wn * 64 + n * 16 + (lane & 15);
            int h = cb >> 6, c6 = cb & 63, sl = c6 >> 3, j = c6 & 7;
#pragma unroll
            for (int r = 0; r < 4; ++r) {
                int row = rb + r;
                sm[h * 8192 + row * 64 + ((sl ^ (row & 7)) << 3) + j] = f2bf(fs * acc[m][n][r]);
            }
        }
    }
    __syncthreads();
    uint4* d4 = (uint4*)(Apk + ((size_t)((kv * 6 + et) * 16 + tt) * 2) * 8192);
    const uint4* s4 = (const uint4*)sm;
#pragma unroll
    for (int p = 0; p < 8; ++p) d4[p * 256 + tid] = s4[p * 256 + tid];
}

// ---------------- stage B v7: D-trick + T-shared staging, sub-steps (jjs, h, sign) ----------------
// Unit (et, zc, i1): jj in {2zc, 2zc+1}; kv24 in [0,24); per kv: rem = jjs*4 + h*2 + sign.
// The sign pair shares ONE T image (staged once per pair); avg 6 loads/step vs 8.
// Gates: even step vmcnt(4), odd step vmcnt(8) — loads never drain to 0 mid-loop.
__global__ __launch_bounds__(256, 2)
void k_gemm_Bv7(const ushort_t* __restrict__ Tpk, const ushort_t* __restrict__ Apk,
                float* __restrict__ outz) {
    __shared__ ushort_t smem[4][8192];       // [0..1] = Tb dbuf, [2..3] = Ab dbuf

    int bid = blockIdx.x;                    // bijective XCD swizzle: 432 = 8*54
    int lid = (bid & 7) * 54 + (bid >> 3);
    int et = lid / 72;
    int r = lid % 72;
    int zc = 0;                              // group prefix P(z) = z*(17-z)
#pragma unroll
    for (int z = 1; z < 8; ++z) if (r >= z * (17 - z)) zc = z;
    int i1 = 2 * zc + (r - zc * (17 - zc));
    int jlo = zc * 2;

    int tid = threadIdx.x, lane = tid & 63, wave = tid >> 6;
    int wm = wave >> 1, wn = wave & 1;

    f32x4 accp[4][4], accm[4][4];
#pragma unroll
    for (int m = 0; m < 4; ++m)
#pragma unroll
        for (int n = 0; n < 4; ++n) {
            accp[m][n] = (f32x4){0.f, 0.f, 0.f, 0.f};
            accm[m][n] = (f32x4){0.f, 0.f, 0.f, 0.f};
        }

    // T slot for (i1, jj): i1 - jj + 1; padded jj = i1+1 -> slot 0 = zeros
    auto timg = [&](int kv24, int jjs, int h) -> const ushort_t* {
        return Tpk + ((size_t)((kv24 * 17 + (i1 - (jlo + jjs) + 1)) * 2 + h)) * 8192;
    };
    auto aimg = [&](int kv24, int sign, int jjs, int h) -> const ushort_t* {
        return Apk + ((size_t)((((kv24 + KF * sign) * 6 + et) * 16 + (jlo + jjs)) * 2 + h)) * 8192;
    };
    auto stage4 = [&](const ushort_t* src, ushort_t* dst) {
        const char* s = (const char*)src + wave * 4096 + lane * 16;
        char* l = (char*)dst + wave * 4096;
#pragma unroll
        for (int p = 0; p < 4; ++p)
            __builtin_amdgcn_global_load_lds((const glb_u32*)(s + p * 1024),
                                             (lds_u32*)(l + p * 1024), 16, 0, 0);
    };

    // prologue: T(kv0,jj0,h0) and A(kv0,s0,jj0,h0) into buffer 0
    stage4(timg(0, 0, 0), smem[0]);
    stage4(aimg(0, 0, 0, 0), smem[2]);

    for (int kv24 = 0; kv24 < KF; ++kv24) {
#pragma unroll
        for (int rem = 0; rem < 8; ++rem) {           // rem = jjs*4 + h*2 + sign
            const int sign = rem & 1;
            const int tbuf = (rem >> 1) & 1;          // pair parity (kv24*4 even)
            const int abuf = rem & 1;                 // step parity
            const int nrem = (rem + 1) & 7;
            const int njjs = nrem >> 2, nh = (nrem >> 1) & 1, nsign = nrem & 1;
            int nkv = kv24 + (rem == 7);
            bool more = (nkv < KF);

            if (more) {
                if (sign) stage4(timg(nkv, njjs, nh), smem[tbuf ^ 1]);   // next pair's T
                stage4(aimg(nkv, nsign, njjs, nh), smem[2 + (abuf ^ 1)]);
                if (sign) { asm volatile("s_waitcnt vmcnt(8)" ::: "memory"); }
                else      { asm volatile("s_waitcnt vmcnt(4)" ::: "memory"); }
            } else {
                asm volatile("s_waitcnt vmcnt(0)" ::: "memory");
            }
            __builtin_amdgcn_s_barrier();
            __builtin_amdgcn_sched_barrier(0);

            const ushort_t* As = smem[tbuf];
            const ushort_t* Bs = smem[2 + abuf];
            short8 av[2][4], bv[2][4];
#pragma unroll
            for (int kk = 0; kk < 2; ++kk) {
                int slot = kk * 4 + (lane >> 4);
#pragma unroll
                for (int m = 0; m < 4; ++m) {
                    int row = wm * 64 + m * 16 + (lane & 15);
                    av[kk][m] = *(const short8*)(As + row * 64 + ((slot ^ (row & 7)) << 3));
                }
#pragma unroll
                for (int n = 0; n < 4; ++n) {
                    int row = wn * 64 + n * 16 + (lane & 15);
                    bv[kk][n] = *(const short8*)(Bs + row * 64 + ((slot ^ (row & 7)) << 3));
                }
            }

            asm volatile("s_waitcnt lgkmcnt(0)" ::: "memory");
            __builtin_amdgcn_sched_barrier(0);

            __builtin_amdgcn_s_setprio(1);
            if (sign == 0) {                          // static: rem unrolled
#pragma unroll
                for (int kk = 0; kk < 2; ++kk)
#pragma unroll
                    for (int m = 0; m < 4; ++m)
#pragma unroll
                        for (int n = 0; n < 4; ++n)
                            accp[m][n] = __builtin_amdgcn_mfma_f32_16x16x32_bf16(av[kk][m], bv[kk][n], accp[m][n], 0, 0, 0);
            } else {
#pragma unroll
                for (int kk = 0; kk < 2; ++kk)
#pragma unroll
                    for (int m = 0; m < 4; ++m)
#pragma unroll
                        for (int n = 0; n < 4; ++n)
                            accm[m][n] = __builtin_amdgcn_mfma_f32_16x16x32_bf16(av[kk][m], bv[kk][n], accm[m][n], 0, 0, 0);
            }
            __builtin_amdgcn_s_setprio(0);
            __builtin_amdgcn_s_barrier();
        }
    }

    // epilogue: out = accp + D*accm; row = rb + r4 (rb even) -> sign = (-1)^r4
    float* dst = outz + ((size_t)zc * SEQ + (size_t)i1 * 128) * DDIM + et * 128;
#pragma unroll
    for (int m = 0; m < 4; ++m) {
        int rb = wm * 64 + m * 16 + ((lane >> 4) << 2);
#pragma unroll
        for (int n = 0; n < 4; ++n) {
            int cb = wn * 64 + n * 16 + (lane & 15);
#pragma unroll
            for (int r4 = 0; r4 < 4; ++r4) {
                float vm = accm[m][n][r4];
                float v = accp[m][n][r4] + ((r4 & 1) ? -vm : vm);
                dst[(size_t)(rb + r4) * DDIM + cb] = v;
            }
        }
    }
}

// sum only z-slices that were written for this row: zc <= srow>>8
__global__ void k_reduce(const float* __restrict__ outz, float* __restrict__ out, int n4) {
    int idx = blockIdx.x * blockDim.x + threadIdx.x;
    if (idx < n4) {
        int srow = idx / (DDIM / 4);
        int zmax = srow >> 8;
        if (zmax > NZC - 1) zmax = NZC - 1;
        float4 s = ((const float4*)outz)[idx];
        for (int z = 1; z <= zmax; ++z) {
            float4 t = ((const float4*)(outz + (size_t)z * SEQ * DDIM))[idx];
            s.x += t.x; s.y += t.y; s.z += t.z; s.w += t.w;
        }
        ((float4*)out)[idx] = s;
    }
}

extern "C" void kernel_launch(void* const* d_in, const int* in_sizes, int n_in,
                              void* d_out, int out_size, void* d_ws, size_t ws_size,
                              hipStream_t stream) {
    (void)in_sizes; (void)n_in;
    const float* x   = (const float*)d_in[0];
    const float* phi = (const float*)d_in[1];
    const float* Mp  = (const float*)d_in[2];
    const float* Mm  = (const float*)d_in[3];
    float* out = (float*)d_out;

    char* ws = (char*)d_ws;
    size_t off = 0;
    auto alloc = [&](size_t bytes) { size_t o = off; off += (bytes + 255) & ~(size_t)255; return o; };
    size_t o_xpk = alloc((size_t)16 * 12 * 8192 * 2);                // 3.0 MB
    size_t o_Mpk = alloc((size_t)NKV * 6 * 12 * 8192 * 2);           // 56.6 MB (aliased by outz)
    size_t o_Tpk = alloc((size_t)KF * 17 * 2 * 8192 * 2);            // 13.4 MB (plus-only)
    size_t o_Apk = alloc((size_t)NKV * 6 * 16 * 2 * 8192 * 2);       // 151.0 MB
    if (off > ws_size) {   // should never happen (~224 MB total; prior rounds proved fits)
        hipMemsetAsync(d_out, 0, (size_t)out_size * 4, stream);
        return;
    }

    ushort_t* xpk = (ushort_t*)(ws + o_xpk);
    ushort_t* Mpk = (ushort_t*)(ws + o_Mpk);
    ushort_t* Tpk = (ushort_t*)(ws + o_Tpk);
    ushort_t* Apk = (ushort_t*)(ws + o_Apk);
    float*   outz = (float*)(ws + o_Mpk);   // alias: Mpk dead after gemm_A; 50.3 <= 56.6 MB

    k_prep<<<192 + 3456 + KF * 17, 256, 0, stream>>>(x, Mp, Mm, phi, xpk, Mpk, Tpk);
    k_gemm_A<<<NKV * 96, 256, 0, stream>>>(Mpk, xpk, Apk);
    k_gemm_Bv7<<<432, 256, 0, stream>>>(Tpk, Apk, outz);
    int n4 = SEQ * DDIM / 4;
    k_reduce<<<(n4 + 255) / 256, 256, 0, stream>>>(outz, out, n4);
}